// Round 1
// baseline (2677.060 us; speedup 1.0000x reference)
//
#include <hip/hip_runtime.h>
#include <hip/hip_bf16.h>

constexpr int C_B   = 64;
constexpr int C_NPG = 512;
constexpr int C_N   = 32768;
constexpr int C_E   = 524288;
constexpr int C_L   = 16;
constexpr int C_H   = 256;
constexpr int C_P   = 128;
constexpr int C_K1  = 256;
constexpr int C_K2  = 128;

// ---------------- edge weights + degree ----------------
__global__ void k_edge_w(const float* __restrict__ ea, const int* __restrict__ dst,
                         float* __restrict__ w, float* __restrict__ deg) {
    int e = blockIdx.x * blockDim.x + threadIdx.x;
    if (e < C_E) {
        float ww = 0.5f * (ea[2 * e] + ea[2 * e + 1]);
        w[e] = ww;
        atomicAdd(&deg[dst[e]], ww);
    }
}

// ---------------- ST encoder: masked mean of token embeddings ----------------
__global__ void k_st_encode(const int* __restrict__ tokens, const float* __restrict__ emb,
                            float* __restrict__ X) {
    int n = blockIdx.x;
    int h = threadIdx.x;
    __shared__ int tok[C_L];
    if (h < C_L) tok[h] = tokens[n * C_L + h];
    __syncthreads();
    float acc = 0.f;
    int cnt = 0;
    #pragma unroll
    for (int t = 0; t < C_L; ++t) {
        int tk = tok[t];               // uniform across block -> no divergence
        if (tk != 0) { acc += emb[(size_t)tk * C_H + h]; cnt++; }
    }
    X[(size_t)n * C_H + h] = acc / fmaxf((float)cnt, 1.f);
}

// ---------------- fp32 matmul C[rows,256] = A[rows,256] @ W[256,256] ----------------
__global__ void k_matmul(const float* __restrict__ A, const float* __restrict__ W,
                         float* __restrict__ C) {
    __shared__ __align__(16) float As[16][68];   // transposed tile, padded
    __shared__ __align__(16) float Bs[16][64];
    int t  = threadIdx.x;
    int tx = t % 16, ty = t / 16;
    int row0 = blockIdx.y * 64;
    int col0 = blockIdx.x * 64;
    float acc[4][4] = {};
    for (int k0 = 0; k0 < C_H; k0 += 16) {
        {   // A tile 64x16 -> transposed
            int i  = t / 4;
            int kk = (t % 4) * 4;
            float4 av = *(const float4*)&A[(size_t)(row0 + i) * C_H + k0 + kk];
            As[kk + 0][i] = av.x; As[kk + 1][i] = av.y;
            As[kk + 2][i] = av.z; As[kk + 3][i] = av.w;
        }
        {   // W tile 16x64
            int kk = t / 16;
            int j  = (t % 16) * 4;
            *(float4*)&Bs[kk][j] = *(const float4*)&W[(size_t)(k0 + kk) * C_H + col0 + j];
        }
        __syncthreads();
        #pragma unroll
        for (int kk = 0; kk < 16; ++kk) {
            float4 a = *(const float4*)&As[kk][ty * 4];
            float4 b = *(const float4*)&Bs[kk][tx * 4];
            float av[4] = {a.x, a.y, a.z, a.w};
            float bv[4] = {b.x, b.y, b.z, b.w};
            #pragma unroll
            for (int r = 0; r < 4; ++r)
                #pragma unroll
                for (int c = 0; c < 4; ++c) acc[r][c] += av[r] * bv[c];
        }
        __syncthreads();
    }
    #pragma unroll
    for (int r = 0; r < 4; ++r) {
        float4 v = make_float4(acc[r][0], acc[r][1], acc[r][2], acc[r][3]);
        *(float4*)&C[(size_t)(row0 + ty * 4 + r) * C_H + col0 + tx * 4] = v;
    }
}

// ---------------- AGG init: self-loop + bias ----------------
__global__ void k_agg_init(const float* __restrict__ Hm, const float* __restrict__ deg,
                           const float* __restrict__ bias, float* __restrict__ AGG, int n) {
    int i = blockIdx.x * blockDim.x + threadIdx.x;
    if (i < n * C_H) {
        int node = i >> 8;
        int h    = i & 255;
        AGG[i] = Hm[i] / (deg[node] + 1.f) + bias[h];
    }
}

// ---------------- edge scatter: AGG[dst] += norm * H[src] ----------------
__global__ void k_scatter(const float* __restrict__ Hm, const int* __restrict__ src,
                          const int* __restrict__ dst, const float* __restrict__ w,
                          const float* __restrict__ deg, float* __restrict__ AGG) {
    int e    = blockIdx.x * 4 + (threadIdx.x >> 6);
    int lane = threadIdx.x & 63;
    float ww = w[e];
    if (ww == 0.f) return;                       // masked edge contributes nothing
    int s = src[e], d = dst[e];
    float norm = rsqrtf(deg[s] + 1.f) * ww * rsqrtf(deg[d] + 1.f);
    float4 hv = *(const float4*)&Hm[(size_t)s * C_H + lane * 4];
    float* dp = &AGG[(size_t)d * C_H + lane * 4];
    atomicAdd(dp + 0, norm * hv.x);
    atomicAdd(dp + 1, norm * hv.y);
    atomicAdd(dp + 2, norm * hv.z);
    atomicAdd(dp + 3, norm * hv.w);
}

__global__ void k_relu(float* __restrict__ X, int n) {
    int i = blockIdx.x * blockDim.x + threadIdx.x;
    if (i < n) X[i] = fmaxf(X[i], 0.f);
}

// ---------------- top-k pooling: score, per-graph bitonic sort, keep-set ----------------
template <int NPER, int KKEEP>
__global__ void k_pool(const float* __restrict__ X, const float* __restrict__ p,
                       int* __restrict__ new_of_old, int* __restrict__ old_of_new,
                       float* __restrict__ gate) {
    int g = blockIdx.x;
    int t = threadIdx.x;
    __shared__ float sv[NPER];
    __shared__ int   si[NPER];
    float pn = 0.f, dt = 0.f;
    const float* xr = &X[(size_t)(g * NPER + t) * C_H];
    for (int k = 0; k < C_H; k += 4) {
        float4 pv = *(const float4*)&p[k];
        float4 xv = *(const float4*)&xr[k];
        pn += pv.x * pv.x + pv.y * pv.y + pv.z * pv.z + pv.w * pv.w;
        dt += pv.x * xv.x + pv.y * xv.y + pv.z * xv.z + pv.w * xv.w;
    }
    sv[t] = dt / sqrtf(pn);
    si[t] = t;
    __syncthreads();
    // bitonic sort, descending
    for (int k = 2; k <= NPER; k <<= 1) {
        for (int j = k >> 1; j > 0; j >>= 1) {
            int ixj = t ^ j;
            if (ixj > t) {
                bool desc = ((t & k) == 0);
                float a = sv[t], b = sv[ixj];
                bool sw = desc ? (a < b) : (a > b);
                if (sw) {
                    sv[t] = b; sv[ixj] = a;
                    int tmp = si[t]; si[t] = si[ixj]; si[ixj] = tmp;
                }
            }
            __syncthreads();
        }
    }
    int old_global = g * NPER + si[t];
    if (t < KKEEP) {
        new_of_old[old_global]    = g * KKEEP + t;
        old_of_new[g * KKEEP + t] = old_global;
        gate[g * KKEEP + t]       = tanhf(sv[t]);
    } else {
        new_of_old[old_global] = -1;
    }
}

// ---------------- gather kept nodes, apply tanh gate ----------------
__global__ void k_gather(const float* __restrict__ X, const int* __restrict__ old_of_new,
                         const float* __restrict__ gate, float* __restrict__ Xn, int nnew) {
    int i = blockIdx.x * blockDim.x + threadIdx.x;
    if (i >= nnew * 64) return;
    int nn = i >> 6;
    int h4 = (i & 63) * 4;
    float4 v = *(const float4*)&X[(size_t)old_of_new[nn] * C_H + h4];
    float gt = gate[nn];
    v.x *= gt; v.y *= gt; v.z *= gt; v.w *= gt;
    *(float4*)&Xn[(size_t)nn * C_H + h4] = v;
}

// ---------------- edge remap after pool 1 ----------------
__global__ void k_remap(const int* __restrict__ src, const int* __restrict__ dst,
                        const float* __restrict__ w, const int* __restrict__ noo,
                        int* __restrict__ src1, int* __restrict__ dst1,
                        float* __restrict__ w1, float* __restrict__ deg1) {
    int e = blockIdx.x * blockDim.x + threadIdx.x;
    if (e >= C_E) return;
    int ns = noo[src[e]], nd = noo[dst[e]];
    bool keep = (ns >= 0) && (nd >= 0);
    src1[e] = keep ? ns : 0;
    dst1[e] = keep ? nd : 0;
    float ww = keep ? w[e] : 0.f;
    w1[e] = ww;
    if (keep) atomicAdd(&deg1[nd], ww);
}

// ---------------- global attention pool ----------------
template <int KN, bool ACC>
__global__ void k_attpool(const float* __restrict__ X, const float* __restrict__ wg,
                          const float* __restrict__ bg, float* __restrict__ out) {
    int g = blockIdx.x;
    int t = threadIdx.x;
    __shared__ float sa[KN];
    __shared__ float red[KN];
    const float* xr = &X[(size_t)(g * KN + t) * C_H];
    float dt = 0.f;
    for (int k = 0; k < C_H; k += 4) {
        float4 wv = *(const float4*)&wg[k];
        float4 xv = *(const float4*)&xr[k];
        dt += wv.x * xv.x + wv.y * xv.y + wv.z * xv.z + wv.w * xv.w;
    }
    dt += bg[0];
    red[t] = dt; __syncthreads();
    for (int s = KN / 2; s > 0; s >>= 1) { if (t < s) red[t] = fmaxf(red[t], red[t + s]); __syncthreads(); }
    float mx = red[0]; __syncthreads();
    float ex = expf(dt - mx);
    red[t] = ex; __syncthreads();
    for (int s = KN / 2; s > 0; s >>= 1) { if (t < s) red[t] += red[t + s]; __syncthreads(); }
    float inv = 1.f / red[0];
    sa[t] = ex * inv;
    __syncthreads();
    for (int h = t; h < C_H; h += KN) {
        float acc = 0.f;
        for (int n = 0; n < KN; ++n) acc += sa[n] * X[(size_t)(g * KN + n) * C_H + h];
        if (ACC) out[g * C_H + h] += acc; else out[g * C_H + h] = acc;
    }
}

// ---------------- projection head + L2 normalize + write both outputs ----------------
__global__ void k_head(const float* __restrict__ outb, const float* __restrict__ Wp1,
                       const float* __restrict__ bp1, const float* __restrict__ Wp2,
                       const float* __restrict__ bp2, float* __restrict__ dout) {
    int g = blockIdx.x;
    int t = threadIdx.x;   // 128
    __shared__ float so[C_H];
    so[t] = outb[g * C_H + t];
    so[t + 128] = outb[g * C_H + t + 128];
    __syncthreads();
    float acc = bp1[t];
    for (int k = 0; k < C_H; ++k) acc += so[k] * Wp1[k * C_P + t];
    float hv = fmaxf(acc, 0.f);
    __shared__ float sh[C_P];
    sh[t] = hv; __syncthreads();
    float lg = bp2[t];
    for (int k = 0; k < C_P; ++k) lg += sh[k] * Wp2[k * C_P + t];
    __shared__ float red[C_P];
    red[t] = lg * lg; __syncthreads();
    for (int s = 64; s > 0; s >>= 1) { if (t < s) red[t] += red[t + s]; __syncthreads(); }
    float nrm = fmaxf(sqrtf(red[0]), 1e-12f);
    dout[g * C_P + t] = lg / nrm;
    dout[C_B * C_P + g * C_H + t]       = so[t];
    dout[C_B * C_P + g * C_H + t + 128] = so[t + 128];
}

extern "C" void kernel_launch(void* const* d_in, const int* in_sizes, int n_in,
                              void* d_out, int out_size, void* d_ws, size_t ws_size,
                              hipStream_t stream) {
    const int*   tokens = (const int*)d_in[0];
    const int*   src    = (const int*)d_in[1];
    const int*   dst    = (const int*)d_in[2];
    const float* eattr  = (const float*)d_in[3];
    const float* emb    = (const float*)d_in[4];
    const float* W0     = (const float*)d_in[5];
    const float* b0     = (const float*)d_in[6];
    const float* W1     = (const float*)d_in[7];
    const float* b1     = (const float*)d_in[8];
    const float* p0     = (const float*)d_in[9];
    const float* p1     = (const float*)d_in[10];
    const float* wg     = (const float*)d_in[11];
    const float* bg     = (const float*)d_in[12];
    const float* Wp1    = (const float*)d_in[13];
    const float* bp1    = (const float*)d_in[14];
    const float* Wp2    = (const float*)d_in[15];
    const float* bp2    = (const float*)d_in[16];
    float* out = (float*)d_out;

    float* f = (float*)d_ws;
    size_t o = 0;
    float* XB    = f + o; o += (size_t)C_N * C_H;        // 8,388,608  (X, then AGG; layer2: H1 | AGG1)
    float* HB    = f + o; o += (size_t)C_N * C_H;        // 8,388,608  (H; layer2: x1 | x2g)
    float* wbuf  = f + o; o += C_E;
    float* degb  = f + o; o += C_N;
    int*   noo   = (int*)(f + o); o += C_N;
    int*   oon   = (int*)(f + o); o += C_B * C_K1;
    float* gate1 = f + o; o += C_B * C_K1;
    int*   src1  = (int*)(f + o); o += C_E;
    int*   dst1  = (int*)(f + o); o += C_E;
    float* w1    = f + o; o += C_E;
    float* deg1  = f + o; o += C_B * C_K1;
    int*   oon2  = (int*)(f + o); o += C_B * C_K2;
    float* gate2 = f + o; o += C_B * C_K2;
    float* outb  = f + o; o += C_B * C_H;

    float* H1   = XB;                                 // 16384*256
    float* AGG1 = XB + (size_t)C_B * C_K1 * C_H;      // 16384*256
    float* x1   = HB;
    float* x2g  = HB + (size_t)C_B * C_K1 * C_H;

    hipMemsetAsync(degb, 0, C_N * sizeof(float), stream);
    hipMemsetAsync(deg1, 0, C_B * C_K1 * sizeof(float), stream);

    k_edge_w<<<C_E / 256, 256, 0, stream>>>(eattr, dst, wbuf, degb);
    k_st_encode<<<C_N, C_H, 0, stream>>>(tokens, emb, XB);

    // ---- layer 1 ----
    k_matmul<<<dim3(4, C_N / 64), 256, 0, stream>>>(XB, W0, HB);
    k_agg_init<<<(C_N * C_H) / 256, 256, 0, stream>>>(HB, degb, b0, XB, C_N);
    k_scatter<<<C_E / 4, 256, 0, stream>>>(HB, src, dst, wbuf, degb, XB);
    k_relu<<<(C_N * C_H) / 256, 256, 0, stream>>>(XB, C_N * C_H);

    k_pool<C_NPG, C_K1><<<C_B, C_NPG, 0, stream>>>(XB, p0, noo, oon, gate1);
    k_gather<<<(C_B * C_K1 * 64) / 256, 256, 0, stream>>>(XB, oon, gate1, x1, C_B * C_K1);
    k_remap<<<C_E / 256, 256, 0, stream>>>(src, dst, wbuf, noo, src1, dst1, w1, deg1);
    k_attpool<C_K1, false><<<C_B, C_K1, 0, stream>>>(x1, wg, bg, outb);

    // ---- layer 2 ----
    k_matmul<<<dim3(4, (C_B * C_K1) / 64), 256, 0, stream>>>(x1, W1, H1);
    k_agg_init<<<(C_B * C_K1 * C_H) / 256, 256, 0, stream>>>(H1, deg1, b1, AGG1, C_B * C_K1);
    k_scatter<<<C_E / 4, 256, 0, stream>>>(H1, src1, dst1, w1, deg1, AGG1);
    k_relu<<<(C_B * C_K1 * C_H) / 256, 256, 0, stream>>>(AGG1, C_B * C_K1 * C_H);

    k_pool<C_K1, C_K2><<<C_B, C_K1, 0, stream>>>(AGG1, p1, noo, oon2, gate2);
    k_gather<<<(C_B * C_K2 * 64) / 256, 256, 0, stream>>>(AGG1, oon2, gate2, x2g, C_B * C_K2);
    k_attpool<C_K2, true><<<C_B, C_K2, 0, stream>>>(x2g, wg, bg, outb);

    // ---- head ----
    k_head<<<C_B, C_P, 0, stream>>>(outb, Wp1, bp1, Wp2, bp2, out);
}

// Round 2
// 1303.033 us; speedup vs baseline: 2.0545x; 2.0545x over previous
//
#include <hip/hip_runtime.h>
#include <hip/hip_bf16.h>

constexpr int C_B   = 64;
constexpr int C_NPG = 512;
constexpr int C_N   = 32768;
constexpr int C_E   = 524288;
constexpr int C_EPG = 8192;
constexpr int C_L   = 16;
constexpr int C_H   = 256;
constexpr int C_P   = 128;
constexpr int C_K1  = 256;
constexpr int C_K2  = 128;

// ---------------- edge weights + degree ----------------
__global__ void k_edge_w(const float* __restrict__ ea, const int* __restrict__ dst,
                         float* __restrict__ w, float* __restrict__ deg) {
    int e = blockIdx.x * blockDim.x + threadIdx.x;
    if (e < C_E) {
        float ww = 0.5f * (ea[2 * e] + ea[2 * e + 1]);
        w[e] = ww;
        atomicAdd(&deg[dst[e]], ww);
    }
}

// ---------------- dinv = rsqrt(deg+1); selfw = 1/(deg+1) (in place over deg) --
__global__ void k_dinv(float* __restrict__ deg, float* __restrict__ dinv, int n) {
    int i = blockIdx.x * blockDim.x + threadIdx.x;
    if (i < n) {
        float d = deg[i] + 1.f;
        dinv[i] = rsqrtf(d);
        deg[i]  = 1.f / d;     // selfw
    }
}

// ---------------- per-edge symmetric norm ----------------
__global__ void k_edge_nrm(const int* __restrict__ src, const int* __restrict__ dst,
                           const float* __restrict__ w, const float* __restrict__ dinv,
                           float* __restrict__ nrm) {
    int e = blockIdx.x * blockDim.x + threadIdx.x;
    if (e < C_E) nrm[e] = dinv[src[e]] * w[e] * dinv[dst[e]];
}

// ---------------- ST encoder: masked mean of token embeddings (float4) -------
__global__ void k_st_encode2(const int* __restrict__ tokens, const float* __restrict__ emb,
                             float* __restrict__ X) {
    __shared__ int tok[4][16];
    int tid = threadIdx.x;
    int nb  = blockIdx.x * 4;
    if (tid < 64) tok[tid >> 4][tid & 15] = tokens[nb * C_L + tid];
    __syncthreads();
    int w    = tid >> 6;
    int lane = tid & 63;
    int n    = nb + w;
    float4 acc = make_float4(0.f, 0.f, 0.f, 0.f);
    int cnt = 0;
    #pragma unroll
    for (int t = 0; t < C_L; ++t) {
        int tk = tok[w][t];                       // wave-uniform
        if (tk != 0) {
            float4 ev = *(const float4*)&emb[(size_t)tk * C_H + lane * 4];
            acc.x += ev.x; acc.y += ev.y; acc.z += ev.z; acc.w += ev.w;
            cnt++;
        }
    }
    float inv = 1.f / fmaxf((float)cnt, 1.f);
    acc.x *= inv; acc.y *= inv; acc.z *= inv; acc.w *= inv;
    *(float4*)&X[(size_t)n * C_H + lane * 4] = acc;
}

// ---------------- fp32 matmul C[rows,256] = A[rows,256] @ W[256,256] ----------
__global__ void k_matmul(const float* __restrict__ A, const float* __restrict__ W,
                         float* __restrict__ C) {
    __shared__ __align__(16) float As[16][68];
    __shared__ __align__(16) float Bs[16][64];
    int t  = threadIdx.x;
    int tx = t % 16, ty = t / 16;
    int row0 = blockIdx.y * 64;
    int col0 = blockIdx.x * 64;
    float acc[4][4] = {};
    for (int k0 = 0; k0 < C_H; k0 += 16) {
        {
            int i  = t / 4;
            int kk = (t % 4) * 4;
            float4 av = *(const float4*)&A[(size_t)(row0 + i) * C_H + k0 + kk];
            As[kk + 0][i] = av.x; As[kk + 1][i] = av.y;
            As[kk + 2][i] = av.z; As[kk + 3][i] = av.w;
        }
        {
            int kk = t / 16;
            int j  = (t % 16) * 4;
            *(float4*)&Bs[kk][j] = *(const float4*)&W[(size_t)(k0 + kk) * C_H + col0 + j];
        }
        __syncthreads();
        #pragma unroll
        for (int kk = 0; kk < 16; ++kk) {
            float4 a = *(const float4*)&As[kk][ty * 4];
            float4 b = *(const float4*)&Bs[kk][tx * 4];
            float av[4] = {a.x, a.y, a.z, a.w};
            float bv[4] = {b.x, b.y, b.z, b.w};
            #pragma unroll
            for (int r = 0; r < 4; ++r)
                #pragma unroll
                for (int c = 0; c < 4; ++c) acc[r][c] += av[r] * bv[c];
        }
        __syncthreads();
    }
    #pragma unroll
    for (int r = 0; r < 4; ++r) {
        float4 v = make_float4(acc[r][0], acc[r][1], acc[r][2], acc[r][3]);
        *(float4*)&C[(size_t)(row0 + ty * 4 + r) * C_H + col0 + tx * 4] = v;
    }
}

// ---------------- fused GCN aggregate: LDS-privatized scatter -----------------
// one WG owns (graph g, node-range half, h-chunk c0): agg tile in LDS (64 KB),
// init = self-loop + bias, scatter edges via ds_add_f32, write out with ReLU.
template <int NPER, int NSPLIT>
__global__ __launch_bounds__(512)
void k_scatter_fused(const float* __restrict__ Hm, const int* __restrict__ srcA,
                     const int* __restrict__ dstA, const float* __restrict__ nrm,
                     const float* __restrict__ selfw, const float* __restrict__ bias,
                     float* __restrict__ Xout) {
    constexpr int NTILE = NPER / NSPLIT;          // 256 both layers -> 64 KB
    __shared__ float agg[NTILE * 64];
    int half  = blockIdx.x;
    int c0    = blockIdx.y * 64;
    int g     = blockIdx.z;
    int node0 = g * NPER + half * NTILE;
    int tid   = threadIdx.x;

    // init: self-loop + bias (float4)
    for (int i4 = tid; i4 < NTILE * 16; i4 += 512) {
        int nl = i4 >> 4;
        int h4 = (i4 & 15) << 2;
        int n  = node0 + nl;
        float4 hv = *(const float4*)&Hm[(size_t)n * C_H + c0 + h4];
        float  sw = selfw[n];
        float4 bv = *(const float4*)&bias[c0 + h4];
        float4 v  = make_float4(fmaf(hv.x, sw, bv.x), fmaf(hv.y, sw, bv.y),
                                fmaf(hv.z, sw, bv.z), fmaf(hv.w, sw, bv.w));
        *(float4*)&agg[nl * 64 + h4] = v;
    }
    __syncthreads();

    int wid  = __builtin_amdgcn_readfirstlane(tid >> 6);
    int lane = tid & 63;
    const float* Hrow = Hm + c0 + lane;
    constexpr int NW = 8;
    constexpr int EW = C_EPG / NW;
    int e0 = g * C_EPG + wid * EW;
    #pragma unroll 4
    for (int i = 0; i < EW; ++i) {
        int e = e0 + i;
        float nm = nrm[e];
        int   d  = dstA[e];
        if (nm != 0.f && d >= node0 && d < node0 + NTILE) {
            int s = srcA[e];
            float val = nm * Hrow[(size_t)s * C_H];
            unsafeAtomicAdd(&agg[(d - node0) * 64 + lane], val);
        }
    }
    __syncthreads();

    // write out with ReLU
    for (int i4 = tid; i4 < NTILE * 16; i4 += 512) {
        int nl = i4 >> 4;
        int h4 = (i4 & 15) << 2;
        float4 v = *(const float4*)&agg[nl * 64 + h4];
        v.x = fmaxf(v.x, 0.f); v.y = fmaxf(v.y, 0.f);
        v.z = fmaxf(v.z, 0.f); v.w = fmaxf(v.w, 0.f);
        *(float4*)&Xout[(size_t)(node0 + nl) * C_H + c0 + h4] = v;
    }
}

// ---------------- top-k pooling ----------------
template <int NPER, int KKEEP>
__global__ void k_pool(const float* __restrict__ X, const float* __restrict__ p,
                       int* __restrict__ new_of_old, int* __restrict__ old_of_new,
                       float* __restrict__ gate) {
    int g = blockIdx.x;
    int t = threadIdx.x;
    __shared__ float sv[NPER];
    __shared__ int   si[NPER];
    float pn = 0.f, dt = 0.f;
    const float* xr = &X[(size_t)(g * NPER + t) * C_H];
    for (int k = 0; k < C_H; k += 4) {
        float4 pv = *(const float4*)&p[k];
        float4 xv = *(const float4*)&xr[k];
        pn += pv.x * pv.x + pv.y * pv.y + pv.z * pv.z + pv.w * pv.w;
        dt += pv.x * xv.x + pv.y * xv.y + pv.z * xv.z + pv.w * xv.w;
    }
    sv[t] = dt / sqrtf(pn);
    si[t] = t;
    __syncthreads();
    for (int k = 2; k <= NPER; k <<= 1) {
        for (int j = k >> 1; j > 0; j >>= 1) {
            int ixj = t ^ j;
            if (ixj > t) {
                bool desc = ((t & k) == 0);
                float a = sv[t], b = sv[ixj];
                bool sw = desc ? (a < b) : (a > b);
                if (sw) {
                    sv[t] = b; sv[ixj] = a;
                    int tmp = si[t]; si[t] = si[ixj]; si[ixj] = tmp;
                }
            }
            __syncthreads();
        }
    }
    int old_global = g * NPER + si[t];
    if (t < KKEEP) {
        new_of_old[old_global]    = g * KKEEP + t;
        old_of_new[g * KKEEP + t] = old_global;
        gate[g * KKEEP + t]       = tanhf(sv[t]);
    } else {
        new_of_old[old_global] = -1;
    }
}

// ---------------- gather kept nodes, apply tanh gate ----------------
__global__ void k_gather(const float* __restrict__ X, const int* __restrict__ old_of_new,
                         const float* __restrict__ gate, float* __restrict__ Xn, int nnew) {
    int i = blockIdx.x * blockDim.x + threadIdx.x;
    if (i >= nnew * 64) return;
    int nn = i >> 6;
    int h4 = (i & 63) * 4;
    float4 v = *(const float4*)&X[(size_t)old_of_new[nn] * C_H + h4];
    float gt = gate[nn];
    v.x *= gt; v.y *= gt; v.z *= gt; v.w *= gt;
    *(float4*)&Xn[(size_t)nn * C_H + h4] = v;
}

// ---------------- edge remap after pool 1 ----------------
__global__ void k_remap(const int* __restrict__ src, const int* __restrict__ dst,
                        const float* __restrict__ w, const int* __restrict__ noo,
                        int* __restrict__ src1, int* __restrict__ dst1,
                        float* __restrict__ w1, float* __restrict__ deg1) {
    int e = blockIdx.x * blockDim.x + threadIdx.x;
    if (e >= C_E) return;
    int ns = noo[src[e]], nd = noo[dst[e]];
    bool keep = (ns >= 0) && (nd >= 0);
    src1[e] = keep ? ns : 0;
    dst1[e] = keep ? nd : 0;
    float ww = keep ? w[e] : 0.f;
    w1[e] = ww;
    if (keep) atomicAdd(&deg1[nd], ww);
}

// ---------------- global attention pool ----------------
template <int KN, bool ACC>
__global__ void k_attpool(const float* __restrict__ X, const float* __restrict__ wg,
                          const float* __restrict__ bg, float* __restrict__ out) {
    int g = blockIdx.x;
    int t = threadIdx.x;
    __shared__ float sa[KN];
    __shared__ float red[KN];
    const float* xr = &X[(size_t)(g * KN + t) * C_H];
    float dt = 0.f;
    for (int k = 0; k < C_H; k += 4) {
        float4 wv = *(const float4*)&wg[k];
        float4 xv = *(const float4*)&xr[k];
        dt += wv.x * xv.x + wv.y * xv.y + wv.z * xv.z + wv.w * xv.w;
    }
    dt += bg[0];
    red[t] = dt; __syncthreads();
    for (int s = KN / 2; s > 0; s >>= 1) { if (t < s) red[t] = fmaxf(red[t], red[t + s]); __syncthreads(); }
    float mx = red[0]; __syncthreads();
    float ex = expf(dt - mx);
    red[t] = ex; __syncthreads();
    for (int s = KN / 2; s > 0; s >>= 1) { if (t < s) red[t] += red[t + s]; __syncthreads(); }
    float inv = 1.f / red[0];
    sa[t] = ex * inv;
    __syncthreads();
    for (int h = t; h < C_H; h += KN) {
        float acc = 0.f;
        for (int n = 0; n < KN; ++n) acc += sa[n] * X[(size_t)(g * KN + n) * C_H + h];
        if (ACC) out[g * C_H + h] += acc; else out[g * C_H + h] = acc;
    }
}

// ---------------- projection head + L2 normalize + write both outputs ---------
__global__ void k_head(const float* __restrict__ outb, const float* __restrict__ Wp1,
                       const float* __restrict__ bp1, const float* __restrict__ Wp2,
                       const float* __restrict__ bp2, float* __restrict__ dout) {
    int g = blockIdx.x;
    int t = threadIdx.x;   // 128
    __shared__ float so[C_H];
    so[t] = outb[g * C_H + t];
    so[t + 128] = outb[g * C_H + t + 128];
    __syncthreads();
    float acc = bp1[t];
    for (int k = 0; k < C_H; ++k) acc += so[k] * Wp1[k * C_P + t];
    float hv = fmaxf(acc, 0.f);
    __shared__ float sh[C_P];
    sh[t] = hv; __syncthreads();
    float lg = bp2[t];
    for (int k = 0; k < C_P; ++k) lg += sh[k] * Wp2[k * C_P + t];
    __shared__ float red[C_P];
    red[t] = lg * lg; __syncthreads();
    for (int s = 64; s > 0; s >>= 1) { if (t < s) red[t] += red[t + s]; __syncthreads(); }
    float nrm = fmaxf(sqrtf(red[0]), 1e-12f);
    dout[g * C_P + t] = lg / nrm;
    dout[C_B * C_P + g * C_H + t]       = so[t];
    dout[C_B * C_P + g * C_H + t + 128] = so[t + 128];
}

extern "C" void kernel_launch(void* const* d_in, const int* in_sizes, int n_in,
                              void* d_out, int out_size, void* d_ws, size_t ws_size,
                              hipStream_t stream) {
    const int*   tokens = (const int*)d_in[0];
    const int*   src    = (const int*)d_in[1];
    const int*   dst    = (const int*)d_in[2];
    const float* eattr  = (const float*)d_in[3];
    const float* emb    = (const float*)d_in[4];
    const float* W0     = (const float*)d_in[5];
    const float* b0     = (const float*)d_in[6];
    const float* W1     = (const float*)d_in[7];
    const float* b1     = (const float*)d_in[8];
    const float* p0     = (const float*)d_in[9];
    const float* p1     = (const float*)d_in[10];
    const float* wg     = (const float*)d_in[11];
    const float* bg     = (const float*)d_in[12];
    const float* Wp1    = (const float*)d_in[13];
    const float* bp1    = (const float*)d_in[14];
    const float* Wp2    = (const float*)d_in[15];
    const float* bp2    = (const float*)d_in[16];
    float* out = (float*)d_out;

    float* f = (float*)d_ws;
    size_t o = 0;
    float* XB    = f + o; o += (size_t)C_N * C_H;   // layer2: H1 | AGG1
    float* HB    = f + o; o += (size_t)C_N * C_H;   // layer2: x1 | x2g
    float* wbuf  = f + o; o += C_E;
    float* nrmb  = f + o; o += C_E;                 // reused for layer-2 norms
    float* degb  = f + o; o += C_N;                 // becomes selfw after k_dinv
    float* dinv  = f + o; o += C_N;                 // reused as dinv1
    int*   noo   = (int*)(f + o); o += C_N;
    int*   oon   = (int*)(f + o); o += C_B * C_K1;
    float* gate1 = f + o; o += C_B * C_K1;
    int*   src1  = (int*)(f + o); o += C_E;
    int*   dst1  = (int*)(f + o); o += C_E;
    float* w1    = f + o; o += C_E;
    float* deg1  = f + o; o += C_B * C_K1;          // becomes selfw1
    int*   oon2  = (int*)(f + o); o += C_B * C_K2;
    float* gate2 = f + o; o += C_B * C_K2;
    float* outb  = f + o; o += C_B * C_H;

    float* H1   = XB;
    float* AGG1 = XB + (size_t)C_B * C_K1 * C_H;
    float* x1   = HB;
    float* x2g  = HB + (size_t)C_B * C_K1 * C_H;

    hipMemsetAsync(degb, 0, C_N * sizeof(float), stream);
    hipMemsetAsync(deg1, 0, C_B * C_K1 * sizeof(float), stream);

    k_edge_w<<<C_E / 256, 256, 0, stream>>>(eattr, dst, wbuf, degb);
    k_st_encode2<<<C_N / 4, 256, 0, stream>>>(tokens, emb, XB);
    k_dinv<<<C_N / 256, 256, 0, stream>>>(degb, dinv, C_N);
    k_edge_nrm<<<C_E / 256, 256, 0, stream>>>(src, dst, wbuf, dinv, nrmb);

    // ---- layer 1 ----
    k_matmul<<<dim3(4, C_N / 64), 256, 0, stream>>>(XB, W0, HB);
    k_scatter_fused<C_NPG, 2><<<dim3(2, 4, C_B), 512, 0, stream>>>(
        HB, src, dst, nrmb, degb, b0, XB);

    k_pool<C_NPG, C_K1><<<C_B, C_NPG, 0, stream>>>(XB, p0, noo, oon, gate1);
    k_gather<<<(C_B * C_K1 * 64) / 256, 256, 0, stream>>>(XB, oon, gate1, x1, C_B * C_K1);
    k_remap<<<C_E / 256, 256, 0, stream>>>(src, dst, wbuf, noo, src1, dst1, w1, deg1);
    k_attpool<C_K1, false><<<C_B, C_K1, 0, stream>>>(x1, wg, bg, outb);

    // ---- layer 2 ----
    k_matmul<<<dim3(4, (C_B * C_K1) / 64), 256, 0, stream>>>(x1, W1, H1);
    k_dinv<<<(C_B * C_K1) / 256, 256, 0, stream>>>(deg1, dinv, C_B * C_K1);
    k_edge_nrm<<<C_E / 256, 256, 0, stream>>>(src1, dst1, w1, dinv, nrmb);
    k_scatter_fused<C_K1, 1><<<dim3(1, 4, C_B), 512, 0, stream>>>(
        H1, src1, dst1, nrmb, deg1, b1, AGG1);

    k_pool<C_K1, C_K2><<<C_B, C_K1, 0, stream>>>(AGG1, p1, noo, oon2, gate2);
    k_gather<<<(C_B * C_K2 * 64) / 256, 256, 0, stream>>>(AGG1, oon2, gate2, x2g, C_B * C_K2);
    k_attpool<C_K2, true><<<C_B, C_K2, 0, stream>>>(x2g, wg, bg, outb);

    // ---- head ----
    k_head<<<C_B, C_P, 0, stream>>>(outb, Wp1, bp1, Wp2, bp2, out);
}

// Round 3
// 522.426 us; speedup vs baseline: 5.1243x; 2.4942x over previous
//
#include <hip/hip_runtime.h>
#include <hip/hip_bf16.h>

constexpr int C_B   = 64;
constexpr int C_NPG = 512;
constexpr int C_N   = 32768;
constexpr int C_E   = 524288;
constexpr int C_EPG = 8192;
constexpr int C_L   = 16;
constexpr int C_H   = 256;
constexpr int C_P   = 128;
constexpr int C_K1  = 256;
constexpr int C_K2  = 128;

// ---------------- edge weights + float degree + int in-degree ----------------
__global__ void k_edge_w(const float* __restrict__ ea, const int* __restrict__ dst,
                         float* __restrict__ w, float* __restrict__ deg,
                         int* __restrict__ indeg) {
    int e = blockIdx.x * blockDim.x + threadIdx.x;
    if (e < C_E) {
        float ww = 0.5f * (ea[2 * e] + ea[2 * e + 1]);
        w[e] = ww;
        int d = dst[e];
        atomicAdd(&deg[d], ww);
        atomicAdd(&indeg[d], 1);
    }
}

// ---------------- dinv = rsqrt(deg+1); selfw = 1/(deg+1) (in place) ----------
__global__ void k_dinv(float* __restrict__ deg, float* __restrict__ dinv, int n) {
    int i = blockIdx.x * blockDim.x + threadIdx.x;
    if (i < n) {
        float d = deg[i] + 1.f;
        dinv[i] = rsqrtf(d);
        deg[i]  = 1.f / d;     // selfw
    }
}

// ---------------- per-graph exclusive scan of in-degree -> rowstart/cursor ---
template <int NPER>
__global__ void k_scan(const int* __restrict__ indeg, int* __restrict__ rowstart,
                       int* __restrict__ cursor) {
    int g = blockIdx.x, t = threadIdx.x;
    __shared__ int s[NPER];
    int v = indeg[g * NPER + t];
    s[t] = v;
    __syncthreads();
    for (int off = 1; off < NPER; off <<= 1) {
        int add = (t >= off) ? s[t - off] : 0;
        __syncthreads();
        s[t] += add;
        __syncthreads();
    }
    int start = g * C_EPG + s[t] - v;      // exclusive prefix, graph-local slab
    rowstart[g * NPER + t] = start;
    cursor[g * NPER + t]   = start;
}

// ---------------- CSR build: scatter edges into dst-sorted slots -------------
__global__ void k_csr_scatter(const int* __restrict__ src, const int* __restrict__ dst,
                              const float* __restrict__ w, const float* __restrict__ dinv,
                              int* __restrict__ cursor, int* __restrict__ csr_src,
                              float* __restrict__ csr_nrm) {
    int e = blockIdx.x * blockDim.x + threadIdx.x;
    if (e >= C_E) return;
    int s = src[e], d = dst[e];
    int slot = atomicAdd(&cursor[d], 1);
    csr_src[slot] = s;
    csr_nrm[slot] = dinv[s] * w[e] * dinv[d];
}

// layer-2 variant: dst1 < 0 marks a masked edge
__global__ void k_csr_scatter2(const int* __restrict__ src1, const int* __restrict__ dst1,
                               const float* __restrict__ w1, const float* __restrict__ dinv,
                               int* __restrict__ cursor, int* __restrict__ csr_src,
                               float* __restrict__ csr_nrm) {
    int e = blockIdx.x * blockDim.x + threadIdx.x;
    if (e >= C_E) return;
    int d = dst1[e];
    if (d < 0) return;
    int s = src1[e];
    int slot = atomicAdd(&cursor[d], 1);
    csr_src[slot] = s;
    csr_nrm[slot] = dinv[s] * w1[e] * dinv[d];
}

// ---------------- GCN aggregate: one wave per dst node, no atomics -----------
__global__ __launch_bounds__(256)
void k_gcn_gather(const float* __restrict__ Hm, const int* __restrict__ rowstart,
                  const int* __restrict__ indeg, const int* __restrict__ csr_src,
                  const float* __restrict__ csr_nrm, const float* __restrict__ selfw,
                  const float* __restrict__ bias, float* __restrict__ Xout, int nnodes) {
    int n    = (blockIdx.x * blockDim.x + threadIdx.x) >> 6;
    int lane = threadIdx.x & 63;
    if (n >= nnodes) return;
    int h4 = lane * 4;
    float4 hv = *(const float4*)&Hm[(size_t)n * C_H + h4];
    float  sw = selfw[n];
    float4 bv = *(const float4*)&bias[h4];
    float4 acc = make_float4(fmaf(hv.x, sw, bv.x), fmaf(hv.y, sw, bv.y),
                             fmaf(hv.z, sw, bv.z), fmaf(hv.w, sw, bv.w));
    int start = rowstart[n], cnt = indeg[n];
    const int*   sp = csr_src + start;
    const float* np = csr_nrm + start;
    #pragma unroll 4
    for (int j = 0; j < cnt; ++j) {
        int   s  = sp[j];
        float nm = np[j];
        float4 xv = *(const float4*)&Hm[(size_t)s * C_H + h4];
        acc.x = fmaf(nm, xv.x, acc.x);
        acc.y = fmaf(nm, xv.y, acc.y);
        acc.z = fmaf(nm, xv.z, acc.z);
        acc.w = fmaf(nm, xv.w, acc.w);
    }
    acc.x = fmaxf(acc.x, 0.f); acc.y = fmaxf(acc.y, 0.f);
    acc.z = fmaxf(acc.z, 0.f); acc.w = fmaxf(acc.w, 0.f);
    *(float4*)&Xout[(size_t)n * C_H + h4] = acc;
}

// ---------------- ST encoder: masked mean of token embeddings (float4) -------
__global__ void k_st_encode2(const int* __restrict__ tokens, const float* __restrict__ emb,
                             float* __restrict__ X) {
    __shared__ int tok[4][16];
    int tid = threadIdx.x;
    int nb  = blockIdx.x * 4;
    if (tid < 64) tok[tid >> 4][tid & 15] = tokens[nb * C_L + tid];
    __syncthreads();
    int w    = tid >> 6;
    int lane = tid & 63;
    int n    = nb + w;
    float4 acc = make_float4(0.f, 0.f, 0.f, 0.f);
    int cnt = 0;
    #pragma unroll
    for (int t = 0; t < C_L; ++t) {
        int tk = tok[w][t];                       // wave-uniform
        if (tk != 0) {
            float4 ev = *(const float4*)&emb[(size_t)tk * C_H + lane * 4];
            acc.x += ev.x; acc.y += ev.y; acc.z += ev.z; acc.w += ev.w;
            cnt++;
        }
    }
    float inv = 1.f / fmaxf((float)cnt, 1.f);
    acc.x *= inv; acc.y *= inv; acc.z *= inv; acc.w *= inv;
    *(float4*)&X[(size_t)n * C_H + lane * 4] = acc;
}

// ---------------- fp32 matmul C[rows,256] = A[rows,256] @ W[256,256] ----------
__global__ void k_matmul(const float* __restrict__ A, const float* __restrict__ W,
                         float* __restrict__ C) {
    __shared__ __align__(16) float As[16][68];
    __shared__ __align__(16) float Bs[16][64];
    int t  = threadIdx.x;
    int tx = t % 16, ty = t / 16;
    int row0 = blockIdx.y * 64;
    int col0 = blockIdx.x * 64;
    float acc[4][4] = {};
    for (int k0 = 0; k0 < C_H; k0 += 16) {
        {
            int i  = t / 4;
            int kk = (t % 4) * 4;
            float4 av = *(const float4*)&A[(size_t)(row0 + i) * C_H + k0 + kk];
            As[kk + 0][i] = av.x; As[kk + 1][i] = av.y;
            As[kk + 2][i] = av.z; As[kk + 3][i] = av.w;
        }
        {
            int kk = t / 16;
            int j  = (t % 16) * 4;
            *(float4*)&Bs[kk][j] = *(const float4*)&W[(size_t)(k0 + kk) * C_H + col0 + j];
        }
        __syncthreads();
        #pragma unroll
        for (int kk = 0; kk < 16; ++kk) {
            float4 a = *(const float4*)&As[kk][ty * 4];
            float4 b = *(const float4*)&Bs[kk][tx * 4];
            float av[4] = {a.x, a.y, a.z, a.w};
            float bv[4] = {b.x, b.y, b.z, b.w};
            #pragma unroll
            for (int r = 0; r < 4; ++r)
                #pragma unroll
                for (int c = 0; c < 4; ++c) acc[r][c] += av[r] * bv[c];
        }
        __syncthreads();
    }
    #pragma unroll
    for (int r = 0; r < 4; ++r) {
        float4 v = make_float4(acc[r][0], acc[r][1], acc[r][2], acc[r][3]);
        *(float4*)&C[(size_t)(row0 + ty * 4 + r) * C_H + col0 + tx * 4] = v;
    }
}

// ---------------- top-k pooling ----------------
template <int NPER, int KKEEP>
__global__ void k_pool(const float* __restrict__ X, const float* __restrict__ p,
                       int* __restrict__ new_of_old, int* __restrict__ old_of_new,
                       float* __restrict__ gate) {
    int g = blockIdx.x;
    int t = threadIdx.x;
    __shared__ float sv[NPER];
    __shared__ int   si[NPER];
    float pn = 0.f, dt = 0.f;
    const float* xr = &X[(size_t)(g * NPER + t) * C_H];
    for (int k = 0; k < C_H; k += 4) {
        float4 pv = *(const float4*)&p[k];
        float4 xv = *(const float4*)&xr[k];
        pn += pv.x * pv.x + pv.y * pv.y + pv.z * pv.z + pv.w * pv.w;
        dt += pv.x * xv.x + pv.y * xv.y + pv.z * xv.z + pv.w * xv.w;
    }
    sv[t] = dt / sqrtf(pn);
    si[t] = t;
    __syncthreads();
    for (int k = 2; k <= NPER; k <<= 1) {
        for (int j = k >> 1; j > 0; j >>= 1) {
            int ixj = t ^ j;
            if (ixj > t) {
                bool desc = ((t & k) == 0);
                float a = sv[t], b = sv[ixj];
                bool sw = desc ? (a < b) : (a > b);
                if (sw) {
                    sv[t] = b; sv[ixj] = a;
                    int tmp = si[t]; si[t] = si[ixj]; si[ixj] = tmp;
                }
            }
            __syncthreads();
        }
    }
    int old_global = g * NPER + si[t];
    if (t < KKEEP) {
        new_of_old[old_global]    = g * KKEEP + t;
        old_of_new[g * KKEEP + t] = old_global;
        gate[g * KKEEP + t]       = tanhf(sv[t]);
    } else {
        new_of_old[old_global] = -1;
    }
}

// ---------------- gather kept nodes, apply tanh gate ----------------
__global__ void k_gather(const float* __restrict__ X, const int* __restrict__ old_of_new,
                         const float* __restrict__ gate, float* __restrict__ Xn, int nnew) {
    int i = blockIdx.x * blockDim.x + threadIdx.x;
    if (i >= nnew * 64) return;
    int nn = i >> 6;
    int h4 = (i & 63) * 4;
    float4 v = *(const float4*)&X[(size_t)old_of_new[nn] * C_H + h4];
    float gt = gate[nn];
    v.x *= gt; v.y *= gt; v.z *= gt; v.w *= gt;
    *(float4*)&Xn[(size_t)nn * C_H + h4] = v;
}

// ---------------- edge remap after pool 1 (dst1 = -1 for masked) -------------
__global__ void k_remap(const int* __restrict__ src, const int* __restrict__ dst,
                        const float* __restrict__ w, const int* __restrict__ noo,
                        int* __restrict__ src1, int* __restrict__ dst1,
                        float* __restrict__ w1, float* __restrict__ deg1,
                        int* __restrict__ indeg1) {
    int e = blockIdx.x * blockDim.x + threadIdx.x;
    if (e >= C_E) return;
    int ns = noo[src[e]], nd = noo[dst[e]];
    bool keep = (ns >= 0) && (nd >= 0);
    src1[e] = ns;
    dst1[e] = keep ? nd : -1;
    w1[e]   = w[e];
    if (keep) {
        atomicAdd(&deg1[nd], w[e]);
        atomicAdd(&indeg1[nd], 1);
    }
}

// ---------------- global attention pool ----------------
template <int KN, bool ACC>
__global__ void k_attpool(const float* __restrict__ X, const float* __restrict__ wg,
                          const float* __restrict__ bg, float* __restrict__ out) {
    int g = blockIdx.x;
    int t = threadIdx.x;
    __shared__ float sa[KN];
    __shared__ float red[KN];
    const float* xr = &X[(size_t)(g * KN + t) * C_H];
    float dt = 0.f;
    for (int k = 0; k < C_H; k += 4) {
        float4 wv = *(const float4*)&wg[k];
        float4 xv = *(const float4*)&xr[k];
        dt += wv.x * xv.x + wv.y * xv.y + wv.z * xv.z + wv.w * xv.w;
    }
    dt += bg[0];
    red[t] = dt; __syncthreads();
    for (int s = KN / 2; s > 0; s >>= 1) { if (t < s) red[t] = fmaxf(red[t], red[t + s]); __syncthreads(); }
    float mx = red[0]; __syncthreads();
    float ex = expf(dt - mx);
    red[t] = ex; __syncthreads();
    for (int s = KN / 2; s > 0; s >>= 1) { if (t < s) red[t] += red[t + s]; __syncthreads(); }
    float inv = 1.f / red[0];
    sa[t] = ex * inv;
    __syncthreads();
    for (int h = t; h < C_H; h += KN) {
        float acc = 0.f;
        for (int n = 0; n < KN; ++n) acc += sa[n] * X[(size_t)(g * KN + n) * C_H + h];
        if (ACC) out[g * C_H + h] += acc; else out[g * C_H + h] = acc;
    }
}

// ---------------- projection head + L2 normalize + write both outputs ---------
__global__ void k_head(const float* __restrict__ outb, const float* __restrict__ Wp1,
                       const float* __restrict__ bp1, const float* __restrict__ Wp2,
                       const float* __restrict__ bp2, float* __restrict__ dout) {
    int g = blockIdx.x;
    int t = threadIdx.x;   // 128
    __shared__ float so[C_H];
    so[t] = outb[g * C_H + t];
    so[t + 128] = outb[g * C_H + t + 128];
    __syncthreads();
    float acc = bp1[t];
    for (int k = 0; k < C_H; ++k) acc += so[k] * Wp1[k * C_P + t];
    float hv = fmaxf(acc, 0.f);
    __shared__ float sh[C_P];
    sh[t] = hv; __syncthreads();
    float lg = bp2[t];
    for (int k = 0; k < C_P; ++k) lg += sh[k] * Wp2[k * C_P + t];
    __shared__ float red[C_P];
    red[t] = lg * lg; __syncthreads();
    for (int s = 64; s > 0; s >>= 1) { if (t < s) red[t] += red[t + s]; __syncthreads(); }
    float nrm = fmaxf(sqrtf(red[0]), 1e-12f);
    dout[g * C_P + t] = lg / nrm;
    dout[C_B * C_P + g * C_H + t]       = so[t];
    dout[C_B * C_P + g * C_H + t + 128] = so[t + 128];
}

extern "C" void kernel_launch(void* const* d_in, const int* in_sizes, int n_in,
                              void* d_out, int out_size, void* d_ws, size_t ws_size,
                              hipStream_t stream) {
    const int*   tokens = (const int*)d_in[0];
    const int*   src    = (const int*)d_in[1];
    const int*   dst    = (const int*)d_in[2];
    const float* eattr  = (const float*)d_in[3];
    const float* emb    = (const float*)d_in[4];
    const float* W0     = (const float*)d_in[5];
    const float* b0     = (const float*)d_in[6];
    const float* W1     = (const float*)d_in[7];
    const float* b1     = (const float*)d_in[8];
    const float* p0     = (const float*)d_in[9];
    const float* p1     = (const float*)d_in[10];
    const float* wg     = (const float*)d_in[11];
    const float* bg     = (const float*)d_in[12];
    const float* Wp1    = (const float*)d_in[13];
    const float* bp1    = (const float*)d_in[14];
    const float* Wp2    = (const float*)d_in[15];
    const float* bp2    = (const float*)d_in[16];
    float* out = (float*)d_out;

    float* f = (float*)d_ws;
    size_t o = 0;
    float* XB     = f + o; o += (size_t)C_N * C_H;   // layer2: H1 | AGG1
    float* HB     = f + o; o += (size_t)C_N * C_H;   // layer2: x1 | x2g
    float* wbuf   = f + o; o += C_E;
    float* degb   = f + o; o += C_N;                 // becomes selfw
    float* dinv   = f + o; o += C_N;                 // reused for layer 2
    int*   indegb = (int*)(f + o); o += C_N;
    int*   rowst  = (int*)(f + o); o += C_N;
    int*   curs   = (int*)(f + o); o += C_N;
    int*   csrs   = (int*)(f + o); o += C_E;
    float* csrn   = f + o; o += C_E;                 // reused for layer 2
    int*   noo    = (int*)(f + o); o += C_N;
    int*   oon    = (int*)(f + o); o += C_B * C_K1;
    float* gate1  = f + o; o += C_B * C_K1;
    int*   src1   = (int*)(f + o); o += C_E;
    int*   dst1   = (int*)(f + o); o += C_E;
    float* w1     = f + o; o += C_E;
    float* deg1   = f + o; o += C_B * C_K1;          // becomes selfw1
    int*   indeg1 = (int*)(f + o); o += C_B * C_K1;
    int*   rowst1 = (int*)(f + o); o += C_B * C_K1;
    int*   curs1  = (int*)(f + o); o += C_B * C_K1;
    int*   oon2   = (int*)(f + o); o += C_B * C_K2;
    float* gate2  = f + o; o += C_B * C_K2;
    float* outb   = f + o; o += C_B * C_H;

    float* H1   = XB;
    float* AGG1 = XB + (size_t)C_B * C_K1 * C_H;
    float* x1   = HB;
    float* x2g  = HB + (size_t)C_B * C_K1 * C_H;

    hipMemsetAsync(degb, 0, C_N * sizeof(float), stream);
    hipMemsetAsync(indegb, 0, C_N * sizeof(int), stream);
    hipMemsetAsync(deg1, 0, C_B * C_K1 * sizeof(float), stream);
    hipMemsetAsync(indeg1, 0, C_B * C_K1 * sizeof(int), stream);

    k_edge_w<<<C_E / 256, 256, 0, stream>>>(eattr, dst, wbuf, degb, indegb);
    k_st_encode2<<<C_N / 4, 256, 0, stream>>>(tokens, emb, XB);
    k_dinv<<<C_N / 256, 256, 0, stream>>>(degb, dinv, C_N);
    k_scan<C_NPG><<<C_B, C_NPG, 0, stream>>>(indegb, rowst, curs);
    k_csr_scatter<<<C_E / 256, 256, 0, stream>>>(src, dst, wbuf, dinv, curs, csrs, csrn);

    // ---- layer 1 ----
    k_matmul<<<dim3(4, C_N / 64), 256, 0, stream>>>(XB, W0, HB);
    k_gcn_gather<<<(C_N * 64) / 256, 256, 0, stream>>>(
        HB, rowst, indegb, csrs, csrn, degb, b0, XB, C_N);

    k_pool<C_NPG, C_K1><<<C_B, C_NPG, 0, stream>>>(XB, p0, noo, oon, gate1);
    k_gather<<<(C_B * C_K1 * 64) / 256, 256, 0, stream>>>(XB, oon, gate1, x1, C_B * C_K1);
    k_remap<<<C_E / 256, 256, 0, stream>>>(src, dst, wbuf, noo, src1, dst1, w1, deg1, indeg1);
    k_attpool<C_K1, false><<<C_B, C_K1, 0, stream>>>(x1, wg, bg, outb);

    // ---- layer 2 ----
    k_matmul<<<dim3(4, (C_B * C_K1) / 64), 256, 0, stream>>>(x1, W1, H1);
    k_dinv<<<(C_B * C_K1) / 256, 256, 0, stream>>>(deg1, dinv, C_B * C_K1);
    k_scan<C_K1><<<C_B, C_K1, 0, stream>>>(indeg1, rowst1, curs1);
    k_csr_scatter2<<<C_E / 256, 256, 0, stream>>>(src1, dst1, w1, dinv, curs1, csrs, csrn);
    k_gcn_gather<<<(C_B * C_K1 * 64) / 256, 256, 0, stream>>>(
        H1, rowst1, indeg1, csrs, csrn, deg1, b1, AGG1, C_B * C_K1);

    k_pool<C_K1, C_K2><<<C_B, C_K1, 0, stream>>>(AGG1, p1, noo, oon2, gate2);
    k_gather<<<(C_B * C_K2 * 64) / 256, 256, 0, stream>>>(AGG1, oon2, gate2, x2g, C_B * C_K2);
    k_attpool<C_K2, true><<<C_B, C_K2, 0, stream>>>(x2g, wg, bg, outb);

    // ---- head ----
    k_head<<<C_B, C_P, 0, stream>>>(outb, Wp1, bp1, Wp2, bp2, out);
}

// Round 4
// 462.281 us; speedup vs baseline: 5.7910x; 1.1301x over previous
//
#include <hip/hip_runtime.h>
#include <hip/hip_bf16.h>

constexpr int C_B   = 64;
constexpr int C_NPG = 512;
constexpr int C_N   = 32768;
constexpr int C_E   = 524288;
constexpr int C_L   = 16;
constexpr int C_H   = 256;
constexpr int C_P   = 128;
constexpr int C_K1  = 256;
constexpr int C_K2  = 128;

typedef __attribute__((ext_vector_type(8)))  short  short8;
typedef __attribute__((ext_vector_type(16))) float  float16;
typedef unsigned short ushort;

__device__ inline void split_bf16(float x, ushort& h, ushort& l) {
    __hip_bfloat16 bh = __float2bfloat16(x);
    float fh = __bfloat162float(bh);
    __hip_bfloat16 bl = __float2bfloat16(x - fh);
    h = __builtin_bit_cast(ushort, bh);
    l = __builtin_bit_cast(ushort, bl);
}

// ---------------- edge weights + float degree + int in-degree ----------------
__global__ void k_edge_w(const float* __restrict__ ea, const int* __restrict__ dst,
                         float* __restrict__ w, float* __restrict__ deg,
                         int* __restrict__ indeg) {
    int e = blockIdx.x * blockDim.x + threadIdx.x;
    if (e < C_E) {
        float ww = 0.5f * (ea[2 * e] + ea[2 * e + 1]);
        w[e] = ww;
        int d = dst[e];
        atomicAdd(&deg[d], ww);
        atomicAdd(&indeg[d], 1);
    }
}

// ---------------- per-graph exclusive scan of in-degree + dinv/selfw ---------
template <int NPER>
__global__ void k_scan(const int* __restrict__ indeg, int* __restrict__ rowstart,
                       int* __restrict__ cursor, float* __restrict__ deg,
                       float* __restrict__ dinv) {
    int g = blockIdx.x, t = threadIdx.x;
    int node = g * NPER + t;
    float d = deg[node] + 1.f;
    dinv[node] = rsqrtf(d);
    deg[node]  = 1.f / d;     // selfw in-place
    __shared__ int s[NPER];
    int v = indeg[node];
    s[t] = v;
    __syncthreads();
    for (int off = 1; off < NPER; off <<= 1) {
        int add = (t >= off) ? s[t - off] : 0;
        __syncthreads();
        s[t] += add;
        __syncthreads();
    }
    int start = g * 8192 + s[t] - v;      // graph-local edge slab
    rowstart[node] = start;
    cursor[node]   = start;
}

// ---------------- CSR build ----------------
__global__ void k_csr_scatter(const int* __restrict__ src, const int* __restrict__ dst,
                              const float* __restrict__ w, const float* __restrict__ dinv,
                              int* __restrict__ cursor, int* __restrict__ csr_src,
                              float* __restrict__ csr_nrm) {
    int e = blockIdx.x * blockDim.x + threadIdx.x;
    if (e >= C_E) return;
    int s = src[e], d = dst[e];
    int slot = atomicAdd(&cursor[d], 1);
    csr_src[slot] = s;
    csr_nrm[slot] = dinv[s] * w[e] * dinv[d];
}

__global__ void k_csr_scatter2(const int* __restrict__ src1, const int* __restrict__ dst1,
                               const float* __restrict__ w1, const float* __restrict__ dinv,
                               int* __restrict__ cursor, int* __restrict__ csr_src,
                               float* __restrict__ csr_nrm) {
    int e = blockIdx.x * blockDim.x + threadIdx.x;
    if (e >= C_E) return;
    int d = dst1[e];
    if (d < 0) return;
    int s = src1[e];
    int slot = atomicAdd(&cursor[d], 1);
    csr_src[slot] = s;
    csr_nrm[slot] = dinv[s] * w1[e] * dinv[d];
}

// ---------------- GCN aggregate: one wave per dst node ----------------
__global__ __launch_bounds__(256)
void k_gcn_gather(const float* __restrict__ Hm, const int* __restrict__ rowstart,
                  const int* __restrict__ indeg, const int* __restrict__ csr_src,
                  const float* __restrict__ csr_nrm, const float* __restrict__ selfw,
                  const float* __restrict__ bias, float* __restrict__ Xout, int nnodes) {
    int n    = (blockIdx.x * blockDim.x + threadIdx.x) >> 6;
    int lane = threadIdx.x & 63;
    if (n >= nnodes) return;
    int h4 = lane * 4;
    float4 hv = *(const float4*)&Hm[(size_t)n * C_H + h4];
    float  sw = selfw[n];
    float4 bv = *(const float4*)&bias[h4];
    float4 acc = make_float4(fmaf(hv.x, sw, bv.x), fmaf(hv.y, sw, bv.y),
                             fmaf(hv.z, sw, bv.z), fmaf(hv.w, sw, bv.w));
    int start = rowstart[n], cnt = indeg[n];
    const int*   sp = csr_src + start;
    const float* np = csr_nrm + start;
    #pragma unroll 4
    for (int j = 0; j < cnt; ++j) {
        int   s  = sp[j];
        float nm = np[j];
        float4 xv = *(const float4*)&Hm[(size_t)s * C_H + h4];
        acc.x = fmaf(nm, xv.x, acc.x);
        acc.y = fmaf(nm, xv.y, acc.y);
        acc.z = fmaf(nm, xv.z, acc.z);
        acc.w = fmaf(nm, xv.w, acc.w);
    }
    acc.x = fmaxf(acc.x, 0.f); acc.y = fmaxf(acc.y, 0.f);
    acc.z = fmaxf(acc.z, 0.f); acc.w = fmaxf(acc.w, 0.f);
    *(float4*)&Xout[(size_t)n * C_H + h4] = acc;
}

// ---------------- frag emission helper: LDS fp32 [32][257] -> hi/lo frag-major
// A-frag layout per mtile (32 rows): halves addr = kst*512 + lane*8 + j,
// where k = kst*16 + (lane>>5)*8 + j, m = mtile*32 + (lane&31).
__device__ inline void emit_frags(const float* Xs, ushort* __restrict__ outh,
                                  ushort* __restrict__ outl, int mtg, int tid) {
    #pragma unroll
    for (int i = 0; i < 4; ++i) {
        int c    = tid + 256 * i;          // 16B chunk id in [0,1024)
        int kst  = c >> 6;
        int lane = c & 63;
        int ml   = lane & 31;
        int kb   = kst * 16 + (lane >> 5) * 8;
        short8 hv, lv;
        #pragma unroll
        for (int j = 0; j < 8; ++j) {
            ushort h, l;
            split_bf16(Xs[ml * 257 + kb + j], h, l);
            hv[j] = (short)h; lv[j] = (short)l;
        }
        size_t base = (size_t)mtg * 8192 + (size_t)c * 8;
        *(short8*)&outh[base] = hv;
        *(short8*)&outl[base] = lv;
    }
}

// ---------------- ST encoder: masked mean -> frag-major hi/lo bf16 ----------
__global__ __launch_bounds__(256)
void k_st_encode3(const int* __restrict__ tokens, const float* __restrict__ emb,
                  ushort* __restrict__ Xh, ushort* __restrict__ Xl) {
    __shared__ float Xs[32 * 257];
    __shared__ int tokS[512];
    int tid = threadIdx.x;
    int blk = blockIdx.x;            // mtile index: 32 nodes
    tokS[tid]       = tokens[(size_t)blk * 512 + tid];
    tokS[tid + 256] = tokens[(size_t)blk * 512 + tid + 256];
    __syncthreads();
    int w    = tid >> 6;
    int lane = tid & 63;
    for (int i = 0; i < 8; ++i) {
        int nl = w * 8 + i;
        float4 acc = make_float4(0.f, 0.f, 0.f, 0.f);
        int cnt = 0;
        #pragma unroll
        for (int t = 0; t < C_L; ++t) {
            int tk = tokS[nl * 16 + t];               // wave-uniform
            if (tk != 0) {
                float4 ev = *(const float4*)&emb[(size_t)tk * C_H + lane * 4];
                acc.x += ev.x; acc.y += ev.y; acc.z += ev.z; acc.w += ev.w;
                cnt++;
            }
        }
        float inv = 1.f / fmaxf((float)cnt, 1.f);
        float* xr = &Xs[nl * 257 + lane * 4];
        xr[0] = acc.x * inv; xr[1] = acc.y * inv;
        xr[2] = acc.z * inv; xr[3] = acc.w * inv;
    }
    __syncthreads();
    emit_frags(Xs, Xh, Xl, blk, tid);
}

// ---------------- W prep: fp32 [256][256] -> frag-major hi/lo bf16 -----------
// B-frag layout: halves addr = ((n>>5)*16 + (k>>4))*512 + ((k>>3)&1)*256 + (n&31)*8 + (k&7)
__global__ void k_wprep(const float* __restrict__ W0, const float* __restrict__ W1,
                        ushort* __restrict__ W0h, ushort* __restrict__ W0l,
                        ushort* __restrict__ W1h, ushort* __restrict__ W1l) {
    int g = blockIdx.x * blockDim.x + threadIdx.x;   // [0, 131072)
    int which = g >> 16;
    int idx = g & 65535;
    int k = idx >> 8, n = idx & 255;
    float x = (which ? W1 : W0)[idx];
    ushort h, l;
    split_bf16(x, h, l);
    size_t a = ((size_t)(n >> 5) * 16 + (k >> 4)) * 512 + ((k >> 3) & 1) * 256
             + (n & 31) * 8 + (k & 7);
    if (which) { W1h[a] = h; W1l[a] = l; }
    else       { W0h[a] = h; W0l[a] = l; }
}

// ---------------- split-bf16 MFMA GEMM: C[M,256] = A[M,256] @ W[256,256] -----
// 3-term: Ah*Bh + Ah*Bl + Al*Bh. Block 128x128, wave tile 64x64 (2x2 of 32x32).
__global__ __launch_bounds__(256)
void k_gemm_mfma(const ushort* __restrict__ Ah, const ushort* __restrict__ Al,
                 const ushort* __restrict__ Bh, const ushort* __restrict__ Bl,
                 float* __restrict__ C) {
    __shared__ short lds[16384];        // A: [0,8192) halves, B: [8192,16384)
    int tid  = threadIdx.x;
    int lane = tid & 63;
    int wid  = tid >> 6;
    int wm   = wid & 1, wn = wid >> 1;
    int mb   = blockIdx.x;              // 128-row chunk
    int nb   = blockIdx.y;              // 128-col half

    float16 acc[2][2];
    #pragma unroll
    for (int mi = 0; mi < 2; ++mi)
        #pragma unroll
        for (int ni = 0; ni < 2; ++ni)
            #pragma unroll
            for (int r = 0; r < 16; ++r) acc[mi][ni][r] = 0.f;

    for (int kc = 0; kc < 8; ++kc) {    // K-chunks of 32
        __syncthreads();
        #pragma unroll
        for (int i = 0; i < 4; ++i) {
            int a  = tid + 256 * i;     // 16B unit in [0,1024)
            int s  = a >> 9;
            int mt = (a >> 7) & 3;
            int k2 = (a >> 6) & 1;
            int ln = a & 63;
            const ushort* ap = (s ? Al : Ah)
                + (((size_t)(mb * 4 + mt) * 16 + kc * 2 + k2) * 64 + ln) * 8;
            *(int4*)&lds[a * 8] = *(const int4*)ap;
            const ushort* bp = (s ? Bl : Bh)
                + (((size_t)(nb * 4 + mt) * 16 + kc * 2 + k2) * 64 + ln) * 8;
            *(int4*)&lds[8192 + a * 8] = *(const int4*)bp;
        }
        __syncthreads();
        #pragma unroll
        for (int k2 = 0; k2 < 2; ++k2) {
            short8 ah[2], al[2], bh[2], bl[2];
            #pragma unroll
            for (int mi = 0; mi < 2; ++mi) {
                int mt = wm * 2 + mi;
                ah[mi] = *(short8*)&lds[((mt * 2 + k2) * 64 + lane) * 8];
                al[mi] = *(short8*)&lds[(((4 + mt) * 2 + k2) * 64 + lane) * 8];
            }
            #pragma unroll
            for (int ni = 0; ni < 2; ++ni) {
                int nt = wn * 2 + ni;
                bh[ni] = *(short8*)&lds[8192 + ((nt * 2 + k2) * 64 + lane) * 8];
                bl[ni] = *(short8*)&lds[8192 + (((4 + nt) * 2 + k2) * 64 + lane) * 8];
            }
            #pragma unroll
            for (int mi = 0; mi < 2; ++mi)
                #pragma unroll
                for (int ni = 0; ni < 2; ++ni) {
                    acc[mi][ni] = __builtin_amdgcn_mfma_f32_32x32x16_bf16(
                        ah[mi], bh[ni], acc[mi][ni], 0, 0, 0);
                    acc[mi][ni] = __builtin_amdgcn_mfma_f32_32x32x16_bf16(
                        ah[mi], bl[ni], acc[mi][ni], 0, 0, 0);
                    acc[mi][ni] = __builtin_amdgcn_mfma_f32_32x32x16_bf16(
                        al[mi], bh[ni], acc[mi][ni], 0, 0, 0);
                }
        }
    }
    // epilogue: C/D layout col=lane&31, row=(r&3)+8*(r>>2)+4*(lane>>5)
    int col = lane & 31;
    int rquad = 4 * (lane >> 5);
    #pragma unroll
    for (int mi = 0; mi < 2; ++mi)
        #pragma unroll
        for (int ni = 0; ni < 2; ++ni) {
            int mbase = mb * 128 + wm * 64 + mi * 32;
            int nbase = nb * 128 + wn * 64 + ni * 32 + col;
            #pragma unroll
            for (int r = 0; r < 16; ++r) {
                int row = (r & 3) + 8 * (r >> 2) + rquad;
                C[(size_t)(mbase + row) * C_H + nbase] = acc[mi][ni][r];
            }
        }
}

// ---------------- top-k pooling ----------------
template <int NPER, int KKEEP>
__global__ void k_pool(const float* __restrict__ X, const float* __restrict__ p,
                       int* __restrict__ new_of_old, int* __restrict__ old_of_new,
                       float* __restrict__ gate) {
    int g = blockIdx.x;
    int t = threadIdx.x;
    __shared__ float sv[NPER];
    __shared__ int   si[NPER];
    float pn = 0.f, dt = 0.f;
    const float* xr = &X[(size_t)(g * NPER + t) * C_H];
    for (int k = 0; k < C_H; k += 4) {
        float4 pv = *(const float4*)&p[k];
        float4 xv = *(const float4*)&xr[k];
        pn += pv.x * pv.x + pv.y * pv.y + pv.z * pv.z + pv.w * pv.w;
        dt += pv.x * xv.x + pv.y * xv.y + pv.z * xv.z + pv.w * xv.w;
    }
    sv[t] = dt / sqrtf(pn);
    si[t] = t;
    __syncthreads();
    for (int k = 2; k <= NPER; k <<= 1) {
        for (int j = k >> 1; j > 0; j >>= 1) {
            int ixj = t ^ j;
            if (ixj > t) {
                bool desc = ((t & k) == 0);
                float a = sv[t], b = sv[ixj];
                bool sw = desc ? (a < b) : (a > b);
                if (sw) {
                    sv[t] = b; sv[ixj] = a;
                    int tmp = si[t]; si[t] = si[ixj]; si[ixj] = tmp;
                }
            }
            __syncthreads();
        }
    }
    int old_global = g * NPER + si[t];
    if (t < KKEEP) {
        new_of_old[old_global]    = g * KKEEP + t;
        old_of_new[g * KKEEP + t] = old_global;
        gate[g * KKEEP + t]       = tanhf(sv[t]);
    } else {
        new_of_old[old_global] = -1;
    }
}

// ---------------- pool-1 gather: fp32 out + frag-major hi/lo for GEMM2 -------
__global__ __launch_bounds__(256)
void k_gather32(const float* __restrict__ X, const int* __restrict__ old_of_new,
                const float* __restrict__ gate, float* __restrict__ Xn,
                ushort* __restrict__ Xnh, ushort* __restrict__ Xnl) {
    __shared__ float Xs[32 * 257];
    __shared__ int   olds[32];
    __shared__ float gts[32];
    int tid = threadIdx.x;
    int blk = blockIdx.x;                // 32 new-nodes
    if (tid < 32) {
        olds[tid] = old_of_new[blk * 32 + tid];
        gts[tid]  = gate[blk * 32 + tid];
    }
    __syncthreads();
    #pragma unroll
    for (int i = 0; i < 8; ++i) {
        int u  = tid + 256 * i;          // [0, 2048)
        int nl = u >> 6;
        int c4 = (u & 63) * 4;
        float4 v = *(const float4*)&X[(size_t)olds[nl] * C_H + c4];
        float g = gts[nl];
        v.x *= g; v.y *= g; v.z *= g; v.w *= g;
        *(float4*)&Xn[((size_t)blk * 32 + nl) * C_H + c4] = v;
        float* xr = &Xs[nl * 257 + c4];
        xr[0] = v.x; xr[1] = v.y; xr[2] = v.z; xr[3] = v.w;
    }
    __syncthreads();
    emit_frags(Xs, Xnh, Xnl, blk, tid);
}

// ---------------- simple gather (pool 2) ----------------
__global__ void k_gather(const float* __restrict__ X, const int* __restrict__ old_of_new,
                         const float* __restrict__ gate, float* __restrict__ Xn, int nnew) {
    int i = blockIdx.x * blockDim.x + threadIdx.x;
    if (i >= nnew * 64) return;
    int nn = i >> 6;
    int h4 = (i & 63) * 4;
    float4 v = *(const float4*)&X[(size_t)old_of_new[nn] * C_H + h4];
    float gt = gate[nn];
    v.x *= gt; v.y *= gt; v.z *= gt; v.w *= gt;
    *(float4*)&Xn[(size_t)nn * C_H + h4] = v;
}

// ---------------- edge remap after pool 1 (dst1 = -1 for masked) -------------
__global__ void k_remap(const int* __restrict__ src, const int* __restrict__ dst,
                        const float* __restrict__ w, const int* __restrict__ noo,
                        int* __restrict__ src1, int* __restrict__ dst1,
                        float* __restrict__ w1, float* __restrict__ deg1,
                        int* __restrict__ indeg1) {
    int e = blockIdx.x * blockDim.x + threadIdx.x;
    if (e >= C_E) return;
    int ns = noo[src[e]], nd = noo[dst[e]];
    bool keep = (ns >= 0) && (nd >= 0);
    src1[e] = ns;
    dst1[e] = keep ? nd : -1;
    w1[e]   = w[e];
    if (keep) {
        atomicAdd(&deg1[nd], w[e]);
        atomicAdd(&indeg1[nd], 1);
    }
}

// ---------------- global attention pool ----------------
template <int KN, bool ACC>
__global__ void k_attpool(const float* __restrict__ X, const float* __restrict__ wg,
                          const float* __restrict__ bg, float* __restrict__ out) {
    int g = blockIdx.x;
    int t = threadIdx.x;
    __shared__ float sa[KN];
    __shared__ float red[KN];
    const float* xr = &X[(size_t)(g * KN + t) * C_H];
    float dt = 0.f;
    for (int k = 0; k < C_H; k += 4) {
        float4 wv = *(const float4*)&wg[k];
        float4 xv = *(const float4*)&xr[k];
        dt += wv.x * xv.x + wv.y * xv.y + wv.z * xv.z + wv.w * xv.w;
    }
    dt += bg[0];
    red[t] = dt; __syncthreads();
    for (int s = KN / 2; s > 0; s >>= 1) { if (t < s) red[t] = fmaxf(red[t], red[t + s]); __syncthreads(); }
    float mx = red[0]; __syncthreads();
    float ex = expf(dt - mx);
    red[t] = ex; __syncthreads();
    for (int s = KN / 2; s > 0; s >>= 1) { if (t < s) red[t] += red[t + s]; __syncthreads(); }
    float inv = 1.f / red[0];
    sa[t] = ex * inv;
    __syncthreads();
    for (int h = t; h < C_H; h += KN) {
        float acc = 0.f;
        for (int n = 0; n < KN; ++n) acc += sa[n] * X[(size_t)(g * KN + n) * C_H + h];
        if (ACC) out[g * C_H + h] += acc; else out[g * C_H + h] = acc;
    }
}

// ---------------- projection head ----------------
__global__ void k_head(const float* __restrict__ outb, const float* __restrict__ Wp1,
                       const float* __restrict__ bp1, const float* __restrict__ Wp2,
                       const float* __restrict__ bp2, float* __restrict__ dout) {
    int g = blockIdx.x;
    int t = threadIdx.x;   // 128
    __shared__ float so[C_H];
    so[t] = outb[g * C_H + t];
    so[t + 128] = outb[g * C_H + t + 128];
    __syncthreads();
    float acc = bp1[t];
    for (int k = 0; k < C_H; ++k) acc += so[k] * Wp1[k * C_P + t];
    float hv = fmaxf(acc, 0.f);
    __shared__ float sh[C_P];
    sh[t] = hv; __syncthreads();
    float lg = bp2[t];
    for (int k = 0; k < C_P; ++k) lg += sh[k] * Wp2[k * C_P + t];
    __shared__ float red[C_P];
    red[t] = lg * lg; __syncthreads();
    for (int s = 64; s > 0; s >>= 1) { if (t < s) red[t] += red[t + s]; __syncthreads(); }
    float nrm = fmaxf(sqrtf(red[0]), 1e-12f);
    dout[g * C_P + t] = lg / nrm;
    dout[C_B * C_P + g * C_H + t]       = so[t];
    dout[C_B * C_P + g * C_H + t + 128] = so[t + 128];
}

extern "C" void kernel_launch(void* const* d_in, const int* in_sizes, int n_in,
                              void* d_out, int out_size, void* d_ws, size_t ws_size,
                              hipStream_t stream) {
    const int*   tokens = (const int*)d_in[0];
    const int*   src    = (const int*)d_in[1];
    const int*   dst    = (const int*)d_in[2];
    const float* eattr  = (const float*)d_in[3];
    const float* emb    = (const float*)d_in[4];
    const float* W0     = (const float*)d_in[5];
    const float* b0     = (const float*)d_in[6];
    const float* W1     = (const float*)d_in[7];
    const float* b1     = (const float*)d_in[8];
    const float* p0     = (const float*)d_in[9];
    const float* p1     = (const float*)d_in[10];
    const float* wg     = (const float*)d_in[11];
    const float* bg     = (const float*)d_in[12];
    const float* Wp1    = (const float*)d_in[13];
    const float* bp1    = (const float*)d_in[14];
    const float* Wp2    = (const float*)d_in[15];
    const float* bp2    = (const float*)d_in[16];
    float* out = (float*)d_out;

    float* f = (float*)d_ws;
    size_t o = 0;
    float*  XB    = f + o; o += (size_t)C_N * C_H;     // gcn1 out; layer2: H1 | AGG1
    float*  HB    = f + o; o += (size_t)C_N * C_H;     // gemm1 out; layer2: x1 | x2g
    ushort* XFh   = (ushort*)(f + o); o += (size_t)C_N * C_H / 2;  // A-frags hi (layer2: x1f hi)
    ushort* XFl   = (ushort*)(f + o); o += (size_t)C_N * C_H / 2;  // A-frags lo
    float*  wbuf  = f + o; o += C_E;
    float*  degb  = f + o; o += C_N;                   // -> selfw
    float*  dinv  = f + o; o += C_N;                   // reused layer 2
    int*    indegb= (int*)(f + o); o += C_N;
    int*    rowst = (int*)(f + o); o += C_N;
    int*    curs  = (int*)(f + o); o += C_N;
    int*    csrs  = (int*)(f + o); o += C_E;
    float*  csrn  = f + o; o += C_E;
    int*    noo   = (int*)(f + o); o += C_N;
    int*    oon   = (int*)(f + o); o += C_B * C_K1;
    float*  gate1 = f + o; o += C_B * C_K1;
    int*    src1  = (int*)(f + o); o += C_E;
    int*    dst1  = (int*)(f + o); o += C_E;
    float*  w1    = f + o; o += C_E;
    float*  deg1  = f + o; o += C_B * C_K1;            // -> selfw1
    int*    indeg1= (int*)(f + o); o += C_B * C_K1;
    int*    rowst1= (int*)(f + o); o += C_B * C_K1;
    int*    curs1 = (int*)(f + o); o += C_B * C_K1;
    int*    oon2  = (int*)(f + o); o += C_B * C_K2;
    float*  gate2 = f + o; o += C_B * C_K2;
    float*  outb  = f + o; o += C_B * C_H;
    ushort* W0h   = (ushort*)(f + o); o += C_H * C_H / 2;
    ushort* W0l   = (ushort*)(f + o); o += C_H * C_H / 2;
    ushort* W1h   = (ushort*)(f + o); o += C_H * C_H / 2;
    ushort* W1l   = (ushort*)(f + o); o += C_H * C_H / 2;

    float* H1   = XB;
    float* AGG1 = XB + (size_t)C_B * C_K1 * C_H;
    float* x1   = HB;
    float* x2g  = HB + (size_t)C_B * C_K1 * C_H;

    hipMemsetAsync(degb, 0, C_N * sizeof(float), stream);
    hipMemsetAsync(indegb, 0, C_N * sizeof(int), stream);
    hipMemsetAsync(deg1, 0, C_B * C_K1 * sizeof(float), stream);
    hipMemsetAsync(indeg1, 0, C_B * C_K1 * sizeof(int), stream);

    k_edge_w<<<C_E / 256, 256, 0, stream>>>(eattr, dst, wbuf, degb, indegb);
    k_wprep<<<131072 / 256, 256, 0, stream>>>(W0, W1, W0h, W0l, W1h, W1l);
    k_st_encode3<<<C_N / 32, 256, 0, stream>>>(tokens, emb, XFh, XFl);
    k_scan<C_NPG><<<C_B, C_NPG, 0, stream>>>(indegb, rowst, curs, degb, dinv);
    k_csr_scatter<<<C_E / 256, 256, 0, stream>>>(src, dst, wbuf, dinv, curs, csrs, csrn);

    // ---- layer 1 ----
    k_gemm_mfma<<<dim3(C_N / 128, 2), 256, 0, stream>>>(XFh, XFl, W0h, W0l, HB);
    k_gcn_gather<<<(C_N * 64) / 256, 256, 0, stream>>>(
        HB, rowst, indegb, csrs, csrn, degb, b0, XB, C_N);

    k_pool<C_NPG, C_K1><<<C_B, C_NPG, 0, stream>>>(XB, p0, noo, oon, gate1);
    k_gather32<<<(C_B * C_K1) / 32, 256, 0, stream>>>(XB, oon, gate1, x1, XFh, XFl);
    k_remap<<<C_E / 256, 256, 0, stream>>>(src, dst, wbuf, noo, src1, dst1, w1, deg1, indeg1);
    k_attpool<C_K1, false><<<C_B, C_K1, 0, stream>>>(x1, wg, bg, outb);

    // ---- layer 2 ----
    k_gemm_mfma<<<dim3((C_B * C_K1) / 128, 2), 256, 0, stream>>>(XFh, XFl, W1h, W1l, H1);
    k_scan<C_K1><<<C_B, C_K1, 0, stream>>>(indeg1, rowst1, curs1, deg1, dinv);
    k_csr_scatter2<<<C_E / 256, 256, 0, stream>>>(src1, dst1, w1, dinv, curs1, csrs, csrn);
    k_gcn_gather<<<(C_B * C_K1 * 64) / 256, 256, 0, stream>>>(
        H1, rowst1, indeg1, csrs, csrn, deg1, b1, AGG1, C_B * C_K1);

    k_pool<C_K1, C_K2><<<C_B, C_K1, 0, stream>>>(AGG1, p1, noo, oon2, gate2);
    k_gather<<<(C_B * C_K2 * 64) / 256, 256, 0, stream>>>(AGG1, oon2, gate2, x2g, C_B * C_K2);
    k_attpool<C_K2, true><<<C_B, C_K2, 0, stream>>>(x2g, wg, bg, outb);

    // ---- head ----
    k_head<<<C_B, C_P, 0, stream>>>(outb, Wp1, bp1, Wp2, bp2, out);
}

// Round 6
// 431.380 us; speedup vs baseline: 6.2058x; 1.0716x over previous
//
#include <hip/hip_runtime.h>
#include <hip/hip_bf16.h>

constexpr int C_B   = 64;
constexpr int C_NPG = 512;
constexpr int C_N   = 32768;
constexpr int C_E   = 524288;
constexpr int C_L   = 16;
constexpr int C_H   = 256;
constexpr int C_P   = 128;
constexpr int C_K1  = 256;
constexpr int C_K2  = 128;
constexpr int C_V   = 50000;

typedef __attribute__((ext_vector_type(8)))  short  short8;
typedef __attribute__((ext_vector_type(16))) float  float16;
typedef unsigned short ushort;
typedef unsigned int   uint;

__device__ inline void split_bf16(float x, ushort& h, ushort& l) {
    __hip_bfloat16 bh = __float2bfloat16(x);
    float fh = __bfloat162float(bh);
    __hip_bfloat16 bl = __float2bfloat16(x - fh);
    h = __builtin_bit_cast(ushort, bh);
    l = __builtin_bit_cast(ushort, bl);
}

// fp16 storage helpers (gather streams): 4x tighter mantissa than bf16
__device__ inline ushort f2h(float x) {
    return __builtin_bit_cast(ushort, (_Float16)x);
}
__device__ inline float4 h4_to_f4(ushort4 v) {
    return make_float4((float)__builtin_bit_cast(_Float16, v.x),
                       (float)__builtin_bit_cast(_Float16, v.y),
                       (float)__builtin_bit_cast(_Float16, v.z),
                       (float)__builtin_bit_cast(_Float16, v.w));
}

// ---------------- init: zero deg/indeg arrays + p-norms ----------------
__global__ void k_init(float* __restrict__ degb, int* __restrict__ indegb,
                       float* __restrict__ deg1, int* __restrict__ indeg1,
                       const float* __restrict__ p0, const float* __restrict__ p1,
                       float* __restrict__ invnp) {
    int b = blockIdx.x, t = threadIdx.x;
    if (b < 128)      degb[b * 256 + t] = 0.f;
    else if (b < 256) indegb[(b - 128) * 256 + t] = 0;
    else if (b < 320) deg1[(b - 256) * 256 + t] = 0.f;
    else if (b < 384) indeg1[(b - 320) * 256 + t] = 0;
    else {
        const float* p = (b == 384) ? p0 : p1;
        __shared__ float r[256];
        float v = p[t];
        r[t] = v * v; __syncthreads();
        for (int s = 128; s; s >>= 1) { if (t < s) r[t] += r[t + s]; __syncthreads(); }
        if (t == 0) invnp[b - 384] = rsqrtf(r[0]);
    }
}

// ---------------- emb fp32 -> fp16 table ----------------
__global__ void k_embcvt(const float* __restrict__ emb, ushort* __restrict__ emb16) {
    int i = (blockIdx.x * 256 + threadIdx.x) * 8;
    float4 a = *(const float4*)&emb[i];
    float4 b = *(const float4*)&emb[i + 4];
    short8 o;
    o[0] = (short)f2h(a.x); o[1] = (short)f2h(a.y);
    o[2] = (short)f2h(a.z); o[3] = (short)f2h(a.w);
    o[4] = (short)f2h(b.x); o[5] = (short)f2h(b.y);
    o[6] = (short)f2h(b.z); o[7] = (short)f2h(b.w);
    *(short8*)&emb16[i] = o;
}

// ---------------- edge weights + float degree + int in-degree ----------------
__global__ void k_edge_w(const float* __restrict__ ea, const int* __restrict__ dst,
                         float* __restrict__ w, float* __restrict__ deg,
                         int* __restrict__ indeg) {
    int e = blockIdx.x * blockDim.x + threadIdx.x;
    if (e < C_E) {
        float ww = 0.5f * (ea[2 * e] + ea[2 * e + 1]);
        w[e] = ww;
        int d = dst[e];
        atomicAdd(&deg[d], ww);
        atomicAdd(&indeg[d], 1);
    }
}

// ---------------- per-graph exclusive scan of in-degree + dinv/selfw ---------
template <int NPER>
__global__ void k_scan(const int* __restrict__ indeg, int* __restrict__ rowstart,
                       int* __restrict__ cursor, float* __restrict__ deg,
                       float* __restrict__ dinv) {
    int g = blockIdx.x, t = threadIdx.x;
    int node = g * NPER + t;
    float d = deg[node] + 1.f;
    dinv[node] = rsqrtf(d);
    deg[node]  = 1.f / d;     // selfw in-place
    __shared__ int s[NPER];
    int v = indeg[node];
    s[t] = v;
    __syncthreads();
    for (int off = 1; off < NPER; off <<= 1) {
        int add = (t >= off) ? s[t - off] : 0;
        __syncthreads();
        s[t] += add;
        __syncthreads();
    }
    int start = g * 8192 + s[t] - v;
    rowstart[node] = start;
    cursor[node]   = start;
}

// ---------------- CSR build ----------------
__global__ void k_csr_scatter(const int* __restrict__ src, const int* __restrict__ dst,
                              const float* __restrict__ w, const float* __restrict__ dinv,
                              int* __restrict__ cursor, int* __restrict__ csr_src,
                              float* __restrict__ csr_nrm) {
    int e = blockIdx.x * blockDim.x + threadIdx.x;
    if (e >= C_E) return;
    int s = src[e], d = dst[e];
    int slot = atomicAdd(&cursor[d], 1);
    csr_src[slot] = s;
    csr_nrm[slot] = dinv[s] * w[e] * dinv[d];
}

__global__ void k_csr_scatter2(const int* __restrict__ src1, const int* __restrict__ dst1,
                               const float* __restrict__ w1, const float* __restrict__ dinv,
                               int* __restrict__ cursor, int* __restrict__ csr_src,
                               float* __restrict__ csr_nrm) {
    int e = blockIdx.x * blockDim.x + threadIdx.x;
    if (e >= C_E) return;
    int d = dst1[e];
    if (d < 0) return;
    int s = src1[e];
    int slot = atomicAdd(&cursor[d], 1);
    csr_src[slot] = s;
    csr_nrm[slot] = dinv[s] * w1[e] * dinv[d];
}

// ---------------- GCN aggregate (fp16 H rows) + fused pool score -------------
__global__ __launch_bounds__(256)
void k_gcn_gather(const ushort* __restrict__ Hm, const int* __restrict__ rowstart,
                  const int* __restrict__ indeg, const int* __restrict__ csr_src,
                  const float* __restrict__ csr_nrm, const float* __restrict__ selfw,
                  const float* __restrict__ bias, const float* __restrict__ p,
                  const float* __restrict__ invnp, float* __restrict__ Xout,
                  float* __restrict__ score, int nnodes) {
    int n    = (blockIdx.x * blockDim.x + threadIdx.x) >> 6;
    int lane = threadIdx.x & 63;
    if (n >= nnodes) return;
    int h4 = lane * 4;
    float4 hv = h4_to_f4(*(const ushort4*)&Hm[(size_t)n * C_H + h4]);
    float  sw = selfw[n];
    float4 bv = *(const float4*)&bias[h4];
    float4 acc = make_float4(fmaf(hv.x, sw, bv.x), fmaf(hv.y, sw, bv.y),
                             fmaf(hv.z, sw, bv.z), fmaf(hv.w, sw, bv.w));
    int start = rowstart[n], cnt = indeg[n];
    const int*   sp = csr_src + start;
    const float* np = csr_nrm + start;
    #pragma unroll 4
    for (int j = 0; j < cnt; ++j) {
        int   s  = sp[j];
        float nm = np[j];
        float4 xv = h4_to_f4(*(const ushort4*)&Hm[(size_t)s * C_H + h4]);
        acc.x = fmaf(nm, xv.x, acc.x);
        acc.y = fmaf(nm, xv.y, acc.y);
        acc.z = fmaf(nm, xv.z, acc.z);
        acc.w = fmaf(nm, xv.w, acc.w);
    }
    acc.x = fmaxf(acc.x, 0.f); acc.y = fmaxf(acc.y, 0.f);
    acc.z = fmaxf(acc.z, 0.f); acc.w = fmaxf(acc.w, 0.f);
    *(float4*)&Xout[(size_t)n * C_H + h4] = acc;
    // fused top-k score: relu(agg) . p / ||p||
    float4 pv = *(const float4*)&p[h4];
    float s = acc.x * pv.x + acc.y * pv.y + acc.z * pv.z + acc.w * pv.w;
    #pragma unroll
    for (int m = 32; m; m >>= 1) s += __shfl_xor(s, m, 64);
    if (lane == 0) score[n] = s * invnp[0];
}

// ---------------- frag emission helper ----------------
__device__ inline void emit_frags(const float* Xs, ushort* __restrict__ outh,
                                  ushort* __restrict__ outl, int mtg, int tid) {
    #pragma unroll
    for (int i = 0; i < 4; ++i) {
        int c    = tid + 256 * i;
        int kst  = c >> 6;
        int lane = c & 63;
        int ml   = lane & 31;
        int kb   = kst * 16 + (lane >> 5) * 8;
        short8 hv, lv;
        #pragma unroll
        for (int j = 0; j < 8; ++j) {
            ushort h, l;
            split_bf16(Xs[ml * 257 + kb + j], h, l);
            hv[j] = (short)h; lv[j] = (short)l;
        }
        size_t base = (size_t)mtg * 8192 + (size_t)c * 8;
        *(short8*)&outh[base] = hv;
        *(short8*)&outl[base] = lv;
    }
}

// ---------------- ST encoder: fp16 table gather -> frag-major hi/lo ----------
__global__ __launch_bounds__(256)
void k_st_encode4(const int* __restrict__ tokens, const ushort* __restrict__ emb16,
                  ushort* __restrict__ Xh, ushort* __restrict__ Xl) {
    __shared__ float Xs[32 * 257];
    __shared__ int tokS[512];
    int tid = threadIdx.x;
    int blk = blockIdx.x;
    tokS[tid]       = tokens[(size_t)blk * 512 + tid];
    tokS[tid + 256] = tokens[(size_t)blk * 512 + tid + 256];
    __syncthreads();
    int w    = tid >> 6;
    int lane = tid & 63;
    for (int i = 0; i < 8; ++i) {
        int nl = w * 8 + i;
        float4 acc = make_float4(0.f, 0.f, 0.f, 0.f);
        int cnt = 0;
        #pragma unroll
        for (int t = 0; t < C_L; ++t) {
            int tk = tokS[nl * 16 + t];               // wave-uniform
            if (tk != 0) {
                float4 ev = h4_to_f4(*(const ushort4*)&emb16[(size_t)tk * C_H + lane * 4]);
                acc.x += ev.x; acc.y += ev.y; acc.z += ev.z; acc.w += ev.w;
                cnt++;
            }
        }
        float inv = 1.f / fmaxf((float)cnt, 1.f);
        float* xr = &Xs[nl * 257 + lane * 4];
        xr[0] = acc.x * inv; xr[1] = acc.y * inv;
        xr[2] = acc.z * inv; xr[3] = acc.w * inv;
    }
    __syncthreads();
    emit_frags(Xs, Xh, Xl, blk, tid);
}

// ---------------- W prep ----------------
__global__ void k_wprep(const float* __restrict__ W0, const float* __restrict__ W1,
                        ushort* __restrict__ W0h, ushort* __restrict__ W0l,
                        ushort* __restrict__ W1h, ushort* __restrict__ W1l) {
    int g = blockIdx.x * blockDim.x + threadIdx.x;
    int which = g >> 16;
    int idx = g & 65535;
    int k = idx >> 8, n = idx & 255;
    float x = (which ? W1 : W0)[idx];
    ushort h, l;
    split_bf16(x, h, l);
    size_t a = ((size_t)(n >> 5) * 16 + (k >> 4)) * 512 + ((k >> 3) & 1) * 256
             + (n & 31) * 8 + (k & 7);
    if (which) { W1h[a] = h; W1l[a] = l; }
    else       { W0h[a] = h; W0l[a] = l; }
}

// ---------------- split-bf16 MFMA GEMM -> fp16 output rows -------------------
__global__ __launch_bounds__(256)
void k_gemm_mfma(const ushort* __restrict__ Ah, const ushort* __restrict__ Al,
                 const ushort* __restrict__ Bh, const ushort* __restrict__ Bl,
                 ushort* __restrict__ C) {
    __shared__ short lds[16384];
    int tid  = threadIdx.x;
    int lane = tid & 63;
    int wid  = tid >> 6;
    int wm   = wid & 1, wn = wid >> 1;
    int mb   = blockIdx.x;
    int nb   = blockIdx.y;

    float16 acc[2][2];
    #pragma unroll
    for (int mi = 0; mi < 2; ++mi)
        #pragma unroll
        for (int ni = 0; ni < 2; ++ni)
            #pragma unroll
            for (int r = 0; r < 16; ++r) acc[mi][ni][r] = 0.f;

    for (int kc = 0; kc < 8; ++kc) {
        __syncthreads();
        #pragma unroll
        for (int i = 0; i < 4; ++i) {
            int a  = tid + 256 * i;
            int s  = a >> 9;
            int mt = (a >> 7) & 3;
            int k2 = (a >> 6) & 1;
            int ln = a & 63;
            const ushort* ap = (s ? Al : Ah)
                + (((size_t)(mb * 4 + mt) * 16 + kc * 2 + k2) * 64 + ln) * 8;
            *(int4*)&lds[a * 8] = *(const int4*)ap;
            const ushort* bp = (s ? Bl : Bh)
                + (((size_t)(nb * 4 + mt) * 16 + kc * 2 + k2) * 64 + ln) * 8;
            *(int4*)&lds[8192 + a * 8] = *(const int4*)bp;
        }
        __syncthreads();
        #pragma unroll
        for (int k2 = 0; k2 < 2; ++k2) {
            short8 ah[2], al[2], bh[2], bl[2];
            #pragma unroll
            for (int mi = 0; mi < 2; ++mi) {
                int mt = wm * 2 + mi;
                ah[mi] = *(short8*)&lds[((mt * 2 + k2) * 64 + lane) * 8];
                al[mi] = *(short8*)&lds[(((4 + mt) * 2 + k2) * 64 + lane) * 8];
            }
            #pragma unroll
            for (int ni = 0; ni < 2; ++ni) {
                int nt = wn * 2 + ni;
                bh[ni] = *(short8*)&lds[8192 + ((nt * 2 + k2) * 64 + lane) * 8];
                bl[ni] = *(short8*)&lds[8192 + (((4 + nt) * 2 + k2) * 64 + lane) * 8];
            }
            #pragma unroll
            for (int mi = 0; mi < 2; ++mi)
                #pragma unroll
                for (int ni = 0; ni < 2; ++ni) {
                    acc[mi][ni] = __builtin_amdgcn_mfma_f32_32x32x16_bf16(
                        ah[mi], bh[ni], acc[mi][ni], 0, 0, 0);
                    acc[mi][ni] = __builtin_amdgcn_mfma_f32_32x32x16_bf16(
                        ah[mi], bl[ni], acc[mi][ni], 0, 0, 0);
                    acc[mi][ni] = __builtin_amdgcn_mfma_f32_32x32x16_bf16(
                        al[mi], bh[ni], acc[mi][ni], 0, 0, 0);
                }
        }
    }
    int col = lane & 31;
    int rquad = 4 * (lane >> 5);
    #pragma unroll
    for (int mi = 0; mi < 2; ++mi)
        #pragma unroll
        for (int ni = 0; ni < 2; ++ni) {
            int mbase = mb * 128 + wm * 64 + mi * 32;
            int nbase = nb * 128 + wn * 64 + ni * 32 + col;
            #pragma unroll
            for (int r = 0; r < 16; ++r) {
                int row = (r & 3) + 8 * (r >> 2) + rquad;
                C[(size_t)(mbase + row) * C_H + nbase] = f2h(acc[mi][ni][r]);
            }
        }
}

// ---------------- top-k pooling (sort-only; scores precomputed) --------------
template <int NPER, int KKEEP>
__global__ void k_pool(const float* __restrict__ score, int* __restrict__ new_of_old,
                       int* __restrict__ old_of_new, float* __restrict__ gate) {
    int g = blockIdx.x;
    int t = threadIdx.x;
    __shared__ float sv[NPER];
    __shared__ int   si[NPER];
    sv[t] = score[g * NPER + t];
    si[t] = t;
    __syncthreads();
    for (int k = 2; k <= NPER; k <<= 1) {
        for (int j = k >> 1; j > 0; j >>= 1) {
            int ixj = t ^ j;
            if (ixj > t) {
                bool desc = ((t & k) == 0);
                float a = sv[t], b = sv[ixj];
                bool sw = desc ? (a < b) : (a > b);
                if (sw) {
                    sv[t] = b; sv[ixj] = a;
                    int tmp = si[t]; si[t] = si[ixj]; si[ixj] = tmp;
                }
            }
            __syncthreads();
        }
    }
    int old_global = g * NPER + si[t];
    if (t < KKEEP) {
        new_of_old[old_global]    = g * KKEEP + t;
        old_of_new[g * KKEEP + t] = old_global;
        gate[g * KKEEP + t]       = tanhf(sv[t]);
    } else {
        new_of_old[old_global] = -1;
    }
}

// ---------------- pool-1 gather: fp32 out + frag-major hi/lo for GEMM2 -------
__global__ __launch_bounds__(256)
void k_gather32(const float* __restrict__ X, const int* __restrict__ old_of_new,
                const float* __restrict__ gate, float* __restrict__ Xn,
                ushort* __restrict__ Xnh, ushort* __restrict__ Xnl) {
    __shared__ float Xs[32 * 257];
    __shared__ int   olds[32];
    __shared__ float gts[32];
    int tid = threadIdx.x;
    int blk = blockIdx.x;
    if (tid < 32) {
        olds[tid] = old_of_new[blk * 32 + tid];
        gts[tid]  = gate[blk * 32 + tid];
    }
    __syncthreads();
    #pragma unroll
    for (int i = 0; i < 8; ++i) {
        int u  = tid + 256 * i;
        int nl = u >> 6;
        int c4 = (u & 63) * 4;
        float4 v = *(const float4*)&X[(size_t)olds[nl] * C_H + c4];
        float g = gts[nl];
        v.x *= g; v.y *= g; v.z *= g; v.w *= g;
        *(float4*)&Xn[((size_t)blk * 32 + nl) * C_H + c4] = v;
        float* xr = &Xs[nl * 257 + c4];
        xr[0] = v.x; xr[1] = v.y; xr[2] = v.z; xr[3] = v.w;
    }
    __syncthreads();
    emit_frags(Xs, Xnh, Xnl, blk, tid);
}

// ---------------- edge remap after pool 1 ----------------
__global__ void k_remap(const int* __restrict__ src, const int* __restrict__ dst,
                        const float* __restrict__ w, const int* __restrict__ noo,
                        int* __restrict__ src1, int* __restrict__ dst1,
                        float* __restrict__ w1, float* __restrict__ deg1,
                        int* __restrict__ indeg1) {
    int e = blockIdx.x * blockDim.x + threadIdx.x;
    if (e >= C_E) return;
    int ns = noo[src[e]], nd = noo[dst[e]];
    bool keep = (ns >= 0) && (nd >= 0);
    src1[e] = ns;
    dst1[e] = keep ? nd : -1;
    w1[e]   = w[e];
    if (keep) {
        atomicAdd(&deg1[nd], w[e]);
        atomicAdd(&indeg1[nd], 1);
    }
}

// ---------------- global attention pool (layer 1) ----------------
template <int KN, bool ACC>
__global__ void k_attpool(const float* __restrict__ X, const float* __restrict__ wg,
                          const float* __restrict__ bg, float* __restrict__ out) {
    int g = blockIdx.x;
    int t = threadIdx.x;
    __shared__ float sa[KN];
    __shared__ float red[KN];
    const float* xr = &X[(size_t)(g * KN + t) * C_H];
    float dt = 0.f;
    for (int k = 0; k < C_H; k += 4) {
        float4 wv = *(const float4*)&wg[k];
        float4 xv = *(const float4*)&xr[k];
        dt += wv.x * xv.x + wv.y * xv.y + wv.z * xv.z + wv.w * xv.w;
    }
    dt += bg[0];
    red[t] = dt; __syncthreads();
    for (int s = KN / 2; s > 0; s >>= 1) { if (t < s) red[t] = fmaxf(red[t], red[t + s]); __syncthreads(); }
    float mx = red[0]; __syncthreads();
    float ex = expf(dt - mx);
    red[t] = ex; __syncthreads();
    for (int s = KN / 2; s > 0; s >>= 1) { if (t < s) red[t] += red[t + s]; __syncthreads(); }
    float inv = 1.f / red[0];
    sa[t] = ex * inv;
    __syncthreads();
    for (int h = t; h < C_H; h += KN) {
        float acc = 0.f;
        for (int n = 0; n < KN; ++n) acc += sa[n] * X[(size_t)(g * KN + n) * C_H + h];
        if (ACC) out[g * C_H + h] += acc; else out[g * C_H + h] = acc;
    }
}

// ---------------- fused pool-2 gather + attention pool -----------------------
__global__ __launch_bounds__(128)
void k_pool2_att(const float* __restrict__ X, const int* __restrict__ oon2,
                 const float* __restrict__ gate2, const float* __restrict__ wg,
                 const float* __restrict__ bg, float* __restrict__ outb) {
    int g = blockIdx.x;
    int t = threadIdx.x;     // 128
    __shared__ int   rows[C_K2];
    __shared__ float gt[C_K2];
    __shared__ float sd[C_K2];
    __shared__ float sa[C_K2];
    __shared__ float red[C_K2];
    rows[t] = oon2[g * C_K2 + t];
    gt[t]   = gate2[g * C_K2 + t];
    __syncthreads();
    int wv = t >> 6, lane = t & 63;
    float4 wv4 = *(const float4*)&wg[lane * 4];
    for (int idx = wv; idx < C_K2; idx += 2) {
        float4 xv = *(const float4*)&X[(size_t)rows[idx] * C_H + lane * 4];
        float s = xv.x * wv4.x + xv.y * wv4.y + xv.z * wv4.z + xv.w * wv4.w;
        #pragma unroll
        for (int m = 32; m; m >>= 1) s += __shfl_xor(s, m, 64);
        if (lane == 0) sd[idx] = gt[idx] * s + bg[0];
    }
    __syncthreads();
    red[t] = sd[t]; __syncthreads();
    for (int s = 64; s; s >>= 1) { if (t < s) red[t] = fmaxf(red[t], red[t + s]); __syncthreads(); }
    float mx = red[0]; __syncthreads();
    float ex = expf(sd[t] - mx);
    red[t] = ex; __syncthreads();
    for (int s = 64; s; s >>= 1) { if (t < s) red[t] += red[t + s]; __syncthreads(); }
    sa[t] = ex / red[0];
    __syncthreads();
    float acc0 = 0.f, acc1 = 0.f;
    for (int n = 0; n < C_K2; ++n) {
        float an = sa[n] * gt[n];
        const float* xr = &X[(size_t)rows[n] * C_H];
        acc0 = fmaf(an, xr[t], acc0);
        acc1 = fmaf(an, xr[t + 128], acc1);
    }
    outb[g * C_H + t]       += acc0;
    outb[g * C_H + t + 128] += acc1;
}

// ---------------- projection head ----------------
__global__ void k_head(const float* __restrict__ outb, const float* __restrict__ Wp1,
                       const float* __restrict__ bp1, const float* __restrict__ Wp2,
                       const float* __restrict__ bp2, float* __restrict__ dout) {
    int g = blockIdx.x;
    int t = threadIdx.x;   // 128
    __shared__ float so[C_H];
    so[t] = outb[g * C_H + t];
    so[t + 128] = outb[g * C_H + t + 128];
    __syncthreads();
    float acc = bp1[t];
    for (int k = 0; k < C_H; ++k) acc += so[k] * Wp1[k * C_P + t];
    float hv = fmaxf(acc, 0.f);
    __shared__ float sh[C_P];
    sh[t] = hv; __syncthreads();
    float lg = bp2[t];
    for (int k = 0; k < C_P; ++k) lg += sh[k] * Wp2[k * C_P + t];
    __shared__ float red[C_P];
    red[t] = lg * lg; __syncthreads();
    for (int s = 64; s > 0; s >>= 1) { if (t < s) red[t] += red[t + s]; __syncthreads(); }
    float nrm = fmaxf(sqrtf(red[0]), 1e-12f);
    dout[g * C_P + t] = lg / nrm;
    dout[C_B * C_P + g * C_H + t]       = so[t];
    dout[C_B * C_P + g * C_H + t + 128] = so[t + 128];
}

extern "C" void kernel_launch(void* const* d_in, const int* in_sizes, int n_in,
                              void* d_out, int out_size, void* d_ws, size_t ws_size,
                              hipStream_t stream) {
    const int*   tokens = (const int*)d_in[0];
    const int*   src    = (const int*)d_in[1];
    const int*   dst    = (const int*)d_in[2];
    const float* eattr  = (const float*)d_in[3];
    const float* emb    = (const float*)d_in[4];
    const float* W0     = (const float*)d_in[5];
    const float* b0     = (const float*)d_in[6];
    const float* W1     = (const float*)d_in[7];
    const float* b1     = (const float*)d_in[8];
    const float* p0     = (const float*)d_in[9];
    const float* p1     = (const float*)d_in[10];
    const float* wg     = (const float*)d_in[11];
    const float* bg     = (const float*)d_in[12];
    const float* Wp1    = (const float*)d_in[13];
    const float* bp1    = (const float*)d_in[14];
    const float* Wp2    = (const float*)d_in[15];
    const float* bp2    = (const float*)d_in[16];
    float* out = (float*)d_out;

    float* f = (float*)d_ws;
    size_t o = 0;
    float*  XB    = f + o; o += (size_t)C_N * C_H;     // gcn1 out; aliased: emb16 early; layer2: AGG1
    float*  HB    = f + o; o += (size_t)C_N * C_H;     // [0..N/2): x1 fp32 | [N/2..): Hhf fp16
    ushort* XFh   = (ushort*)(f + o); o += (size_t)C_N * C_H / 2;
    ushort* XFl   = (ushort*)(f + o); o += (size_t)C_N * C_H / 2;
    float*  wbuf  = f + o; o += C_E;
    float*  degb  = f + o; o += C_N;                   // -> selfw
    float*  dinv  = f + o; o += C_N;
    int*    indegb= (int*)(f + o); o += C_N;
    int*    rowst = (int*)(f + o); o += C_N;
    int*    curs  = (int*)(f + o); o += C_N;
    int*    csrs  = (int*)(f + o); o += C_E;
    float*  csrn  = f + o; o += C_E;
    int*    noo   = (int*)(f + o); o += C_N;
    int*    oon   = (int*)(f + o); o += C_B * C_K1;
    float*  gate1 = f + o; o += C_B * C_K1;
    int*    src1  = (int*)(f + o); o += C_E;
    int*    dst1  = (int*)(f + o); o += C_E;
    float*  w1    = f + o; o += C_E;
    float*  deg1  = f + o; o += C_B * C_K1;            // -> selfw1
    int*    indeg1= (int*)(f + o); o += C_B * C_K1;
    int*    rowst1= (int*)(f + o); o += C_B * C_K1;
    int*    curs1 = (int*)(f + o); o += C_B * C_K1;
    int*    oon2  = (int*)(f + o); o += C_B * C_K2;
    float*  gate2 = f + o; o += C_B * C_K2;
    float*  outb  = f + o; o += C_B * C_H;
    float*  score = f + o; o += C_N;
    float*  invnp = f + o; o += 16;
    ushort* W0h   = (ushort*)(f + o); o += C_H * C_H / 2;
    ushort* W0l   = (ushort*)(f + o); o += C_H * C_H / 2;
    ushort* W1h   = (ushort*)(f + o); o += C_H * C_H / 2;
    ushort* W1l   = (ushort*)(f + o); o += C_H * C_H / 2;

    ushort* emb16 = (ushort*)XB;                       // dead before gcn_gather1 writes XB
    float*  AGG1  = XB;                                // layer-2 gcn out (16384 rows)
    float*  x1    = HB;                                // pool-1 gathered fp32 (16384 rows)
    ushort* Hhf   = (ushort*)(HB + (size_t)C_N * C_H / 2);  // fp16 GEMM out (32768 rows)

    k_init<<<386, 256, 0, stream>>>(degb, indegb, deg1, indeg1, p0, p1, invnp);
    k_embcvt<<<(C_V * C_H) / 2048, 256, 0, stream>>>(emb, emb16);
    k_edge_w<<<C_E / 256, 256, 0, stream>>>(eattr, dst, wbuf, degb, indegb);
    k_wprep<<<131072 / 256, 256, 0, stream>>>(W0, W1, W0h, W0l, W1h, W1l);
    k_st_encode4<<<C_N / 32, 256, 0, stream>>>(tokens, emb16, XFh, XFl);
    k_scan<C_NPG><<<C_B, C_NPG, 0, stream>>>(indegb, rowst, curs, degb, dinv);
    k_csr_scatter<<<C_E / 256, 256, 0, stream>>>(src, dst, wbuf, dinv, curs, csrs, csrn);

    // ---- layer 1 ----
    k_gemm_mfma<<<dim3(C_N / 128, 2), 256, 0, stream>>>(XFh, XFl, W0h, W0l, Hhf);
    k_gcn_gather<<<(C_N * 64) / 256, 256, 0, stream>>>(
        Hhf, rowst, indegb, csrs, csrn, degb, b0, p0, invnp, XB, score, C_N);

    k_pool<C_NPG, C_K1><<<C_B, C_NPG, 0, stream>>>(score, noo, oon, gate1);
    k_gather32<<<(C_B * C_K1) / 32, 256, 0, stream>>>(XB, oon, gate1, x1, XFh, XFl);
    k_remap<<<C_E / 256, 256, 0, stream>>>(src, dst, wbuf, noo, src1, dst1, w1, deg1, indeg1);
    k_attpool<C_K1, false><<<C_B, C_K1, 0, stream>>>(x1, wg, bg, outb);

    // ---- layer 2 ----
    k_gemm_mfma<<<dim3((C_B * C_K1) / 128, 2), 256, 0, stream>>>(XFh, XFl, W1h, W1l, Hhf);
    k_scan<C_K1><<<C_B, C_K1, 0, stream>>>(indeg1, rowst1, curs1, deg1, dinv);
    k_csr_scatter2<<<C_E / 256, 256, 0, stream>>>(src1, dst1, w1, dinv, curs1, csrs, csrn);
    k_gcn_gather<<<(C_B * C_K1 * 64) / 256, 256, 0, stream>>>(
        Hhf, rowst1, indeg1, csrs, csrn, deg1, b1, p1, invnp + 1, AGG1, score, C_B * C_K1);

    k_pool<C_K1, C_K2><<<C_B, C_K1, 0, stream>>>(score, noo, oon2, gate2);
    k_pool2_att<<<C_B, C_K2, 0, stream>>>(AGG1, oon2, gate2, wg, bg, outb);

    // ---- head ----
    k_head<<<C_B, C_P, 0, stream>>>(outb, Wp1, bp1, Wp2, bp2, out);
}

// Round 7
// 405.655 us; speedup vs baseline: 6.5994x; 1.0634x over previous
//
#include <hip/hip_runtime.h>
#include <hip/hip_bf16.h>

constexpr int C_B   = 64;
constexpr int C_NPG = 512;
constexpr int C_N   = 32768;
constexpr int C_E   = 524288;
constexpr int C_L   = 16;
constexpr int C_H   = 256;
constexpr int C_P   = 128;
constexpr int C_K1  = 256;
constexpr int C_K2  = 128;
constexpr int C_V   = 50000;

typedef __attribute__((ext_vector_type(8)))  short  short8;
typedef __attribute__((ext_vector_type(16))) float  float16;
typedef unsigned short ushort;
typedef unsigned int   uint;

__device__ inline void split_bf16(float x, ushort& h, ushort& l) {
    __hip_bfloat16 bh = __float2bfloat16(x);
    float fh = __bfloat162float(bh);
    __hip_bfloat16 bl = __float2bfloat16(x - fh);
    h = __builtin_bit_cast(ushort, bh);
    l = __builtin_bit_cast(ushort, bl);
}

__device__ inline ushort f2h(float x) {
    return __builtin_bit_cast(ushort, (_Float16)x);
}
__device__ inline float4 h4_to_f4(ushort4 v) {
    return make_float4((float)__builtin_bit_cast(_Float16, v.x),
                       (float)__builtin_bit_cast(_Float16, v.y),
                       (float)__builtin_bit_cast(_Float16, v.z),
                       (float)__builtin_bit_cast(_Float16, v.w));
}

// ---------------- fused preprocessing: embcvt | edge_w | wprep | p-norms -----
__global__ void k_pre(const float* __restrict__ emb, ushort* __restrict__ emb16,
                      const float* __restrict__ ea, const int* __restrict__ dst,
                      float* __restrict__ w, float* __restrict__ degb, int* __restrict__ indegb,
                      const float* __restrict__ W0, const float* __restrict__ W1,
                      ushort* __restrict__ W0h, ushort* __restrict__ W0l,
                      ushort* __restrict__ W1h, ushort* __restrict__ W1l,
                      const float* __restrict__ p0, const float* __restrict__ p1,
                      float* __restrict__ invnp) {
    int b = blockIdx.x, t = threadIdx.x;
    __shared__ float r[256];
    if (b < 6250) {                       // emb fp32 -> fp16
        int i = (b * 256 + t) * 8;
        float4 a = *(const float4*)&emb[i];
        float4 c = *(const float4*)&emb[i + 4];
        short8 o;
        o[0] = (short)f2h(a.x); o[1] = (short)f2h(a.y);
        o[2] = (short)f2h(a.z); o[3] = (short)f2h(a.w);
        o[4] = (short)f2h(c.x); o[5] = (short)f2h(c.y);
        o[6] = (short)f2h(c.z); o[7] = (short)f2h(c.w);
        *(short8*)&emb16[i] = o;
    } else if (b < 8298) {                // edge weights + degrees
        int e = (b - 6250) * 256 + t;
        float ww = 0.5f * (ea[2 * e] + ea[2 * e + 1]);
        w[e] = ww;
        int d = dst[e];
        atomicAdd(&degb[d], ww);
        atomicAdd(&indegb[d], 1);
    } else if (b < 8810) {                // W prep -> frag-major hi/lo
        int g = (b - 8298) * 256 + t;
        int which = g >> 16;
        int idx = g & 65535;
        int k = idx >> 8, n = idx & 255;
        float x = (which ? W1 : W0)[idx];
        ushort h, l;
        split_bf16(x, h, l);
        size_t a = ((size_t)(n >> 5) * 16 + (k >> 4)) * 512 + ((k >> 3) & 1) * 256
                 + (n & 31) * 8 + (k & 7);
        if (which) { W1h[a] = h; W1l[a] = l; }
        else       { W0h[a] = h; W0l[a] = l; }
    } else {                              // p-norms
        const float* p = (b == 8810) ? p0 : p1;
        float v = p[t];
        r[t] = v * v; __syncthreads();
        for (int s = 128; s; s >>= 1) { if (t < s) r[t] += r[t + s]; __syncthreads(); }
        if (t == 0) invnp[b - 8810] = rsqrtf(r[0]);
    }
}

// ---------------- per-graph exclusive scan of in-degree + dinv/selfw (L1) ----
template <int NPER>
__global__ void k_scan(const int* __restrict__ indeg, int* __restrict__ rowstart,
                       int* __restrict__ cursor, float* __restrict__ deg,
                       float* __restrict__ dinv) {
    int g = blockIdx.x, t = threadIdx.x;
    int node = g * NPER + t;
    float d = deg[node] + 1.f;
    dinv[node] = rsqrtf(d);
    deg[node]  = 1.f / d;     // selfw in-place
    __shared__ int s[NPER];
    int v = indeg[node];
    s[t] = v;
    __syncthreads();
    for (int off = 1; off < NPER; off <<= 1) {
        int add = (t >= off) ? s[t - off] : 0;
        __syncthreads();
        s[t] += add;
        __syncthreads();
    }
    int start = g * 8192 + s[t] - v;
    rowstart[node] = start;
    cursor[node]   = start;
}

// ---------------- CSR build (layer 1) ----------------
__global__ void k_csr_scatter(const int* __restrict__ src, const int* __restrict__ dst,
                              const float* __restrict__ w, const float* __restrict__ dinv,
                              int* __restrict__ cursor, int* __restrict__ csr_src,
                              float* __restrict__ csr_nrm) {
    int e = blockIdx.x * blockDim.x + threadIdx.x;
    if (e >= C_E) return;
    int s = src[e], d = dst[e];
    int slot = atomicAdd(&cursor[d], 1);
    csr_src[slot] = s;
    csr_nrm[slot] = dinv[s] * w[e] * dinv[d];
}

// ---------------- GCN aggregate (fp16 H rows) + fused pool score -------------
__global__ __launch_bounds__(256)
void k_gcn_gather(const ushort* __restrict__ Hm, const int* __restrict__ rowstart,
                  const int* __restrict__ indeg, const int* __restrict__ csr_src,
                  const float* __restrict__ csr_nrm, const float* __restrict__ selfw,
                  const float* __restrict__ bias, const float* __restrict__ p,
                  const float* __restrict__ invnp, float* __restrict__ Xout,
                  float* __restrict__ score, int nnodes) {
    int n    = (blockIdx.x * blockDim.x + threadIdx.x) >> 6;
    int lane = threadIdx.x & 63;
    if (n >= nnodes) return;
    int h4 = lane * 4;
    float4 hv = h4_to_f4(*(const ushort4*)&Hm[(size_t)n * C_H + h4]);
    float  sw = selfw[n];
    float4 bv = *(const float4*)&bias[h4];
    float4 acc = make_float4(fmaf(hv.x, sw, bv.x), fmaf(hv.y, sw, bv.y),
                             fmaf(hv.z, sw, bv.z), fmaf(hv.w, sw, bv.w));
    int start = rowstart[n], cnt = indeg[n];
    const int*   sp = csr_src + start;
    const float* np = csr_nrm + start;
    #pragma unroll 4
    for (int j = 0; j < cnt; ++j) {
        int   s  = sp[j];
        float nm = np[j];
        float4 xv = h4_to_f4(*(const ushort4*)&Hm[(size_t)s * C_H + h4]);
        acc.x = fmaf(nm, xv.x, acc.x);
        acc.y = fmaf(nm, xv.y, acc.y);
        acc.z = fmaf(nm, xv.z, acc.z);
        acc.w = fmaf(nm, xv.w, acc.w);
    }
    acc.x = fmaxf(acc.x, 0.f); acc.y = fmaxf(acc.y, 0.f);
    acc.z = fmaxf(acc.z, 0.f); acc.w = fmaxf(acc.w, 0.f);
    *(float4*)&Xout[(size_t)n * C_H + h4] = acc;
    float4 pv = *(const float4*)&p[h4];
    float s = acc.x * pv.x + acc.y * pv.y + acc.z * pv.z + acc.w * pv.w;
    #pragma unroll
    for (int m = 32; m; m >>= 1) s += __shfl_xor(s, m, 64);
    if (lane == 0) score[n] = s * invnp[0];
}

// ---------------- ST encoder: fp16 table gather -> frag-major hi/lo ----------
__global__ __launch_bounds__(256)
void k_st_encode4(const int* __restrict__ tokens, const ushort* __restrict__ emb16,
                  ushort* __restrict__ Xh, ushort* __restrict__ Xl) {
    __shared__ float Xs[32 * 257];
    __shared__ int tokS[512];
    int tid = threadIdx.x;
    int blk = blockIdx.x;
    tokS[tid]       = tokens[(size_t)blk * 512 + tid];
    tokS[tid + 256] = tokens[(size_t)blk * 512 + tid + 256];
    __syncthreads();
    int w    = tid >> 6;
    int lane = tid & 63;
    for (int i = 0; i < 8; ++i) {
        int nl = w * 8 + i;
        float4 acc = make_float4(0.f, 0.f, 0.f, 0.f);
        int cnt = 0;
        #pragma unroll
        for (int t = 0; t < C_L; ++t) {
            int tk = tokS[nl * 16 + t];               // wave-uniform
            if (tk != 0) {
                float4 ev = h4_to_f4(*(const ushort4*)&emb16[(size_t)tk * C_H + lane * 4]);
                acc.x += ev.x; acc.y += ev.y; acc.z += ev.z; acc.w += ev.w;
                cnt++;
            }
        }
        float inv = 1.f / fmaxf((float)cnt, 1.f);
        float* xr = &Xs[nl * 257 + lane * 4];
        xr[0] = acc.x * inv; xr[1] = acc.y * inv;
        xr[2] = acc.z * inv; xr[3] = acc.w * inv;
    }
    __syncthreads();
    #pragma unroll
    for (int i = 0; i < 4; ++i) {
        int c    = tid + 256 * i;
        int kst  = c >> 6;
        int ln   = c & 63;
        int ml   = ln & 31;
        int kb   = kst * 16 + (ln >> 5) * 8;
        short8 hv, lv;
        #pragma unroll
        for (int j = 0; j < 8; ++j) {
            ushort h, l;
            split_bf16(Xs[ml * 257 + kb + j], h, l);
            hv[j] = (short)h; lv[j] = (short)l;
        }
        size_t base = (size_t)blk * 8192 + (size_t)c * 8;
        *(short8*)&Xh[base] = hv;
        *(short8*)&Xl[base] = lv;
    }
}

// ---------------- split-bf16 MFMA GEMM -> fp16 output rows -------------------
__global__ __launch_bounds__(256)
void k_gemm_mfma(const ushort* __restrict__ Ah, const ushort* __restrict__ Al,
                 const ushort* __restrict__ Bh, const ushort* __restrict__ Bl,
                 ushort* __restrict__ C) {
    __shared__ short lds[16384];
    int tid  = threadIdx.x;
    int lane = tid & 63;
    int wid  = tid >> 6;
    int wm   = wid & 1, wn = wid >> 1;
    int mb   = blockIdx.x;
    int nb   = blockIdx.y;

    float16 acc[2][2];
    #pragma unroll
    for (int mi = 0; mi < 2; ++mi)
        #pragma unroll
        for (int ni = 0; ni < 2; ++ni)
            #pragma unroll
            for (int r = 0; r < 16; ++r) acc[mi][ni][r] = 0.f;

    for (int kc = 0; kc < 8; ++kc) {
        __syncthreads();
        #pragma unroll
        for (int i = 0; i < 4; ++i) {
            int a  = tid + 256 * i;
            int s  = a >> 9;
            int mt = (a >> 7) & 3;
            int k2 = (a >> 6) & 1;
            int ln = a & 63;
            const ushort* ap = (s ? Al : Ah)
                + (((size_t)(mb * 4 + mt) * 16 + kc * 2 + k2) * 64 + ln) * 8;
            *(int4*)&lds[a * 8] = *(const int4*)ap;
            const ushort* bp = (s ? Bl : Bh)
                + (((size_t)(nb * 4 + mt) * 16 + kc * 2 + k2) * 64 + ln) * 8;
            *(int4*)&lds[8192 + a * 8] = *(const int4*)bp;
        }
        __syncthreads();
        #pragma unroll
        for (int k2 = 0; k2 < 2; ++k2) {
            short8 ah[2], al[2], bh[2], bl[2];
            #pragma unroll
            for (int mi = 0; mi < 2; ++mi) {
                int mt = wm * 2 + mi;
                ah[mi] = *(short8*)&lds[((mt * 2 + k2) * 64 + lane) * 8];
                al[mi] = *(short8*)&lds[(((4 + mt) * 2 + k2) * 64 + lane) * 8];
            }
            #pragma unroll
            for (int ni = 0; ni < 2; ++ni) {
                int nt = wn * 2 + ni;
                bh[ni] = *(short8*)&lds[8192 + ((nt * 2 + k2) * 64 + lane) * 8];
                bl[ni] = *(short8*)&lds[8192 + (((4 + nt) * 2 + k2) * 64 + lane) * 8];
            }
            #pragma unroll
            for (int mi = 0; mi < 2; ++mi)
                #pragma unroll
                for (int ni = 0; ni < 2; ++ni) {
                    acc[mi][ni] = __builtin_amdgcn_mfma_f32_32x32x16_bf16(
                        ah[mi], bh[ni], acc[mi][ni], 0, 0, 0);
                    acc[mi][ni] = __builtin_amdgcn_mfma_f32_32x32x16_bf16(
                        ah[mi], bl[ni], acc[mi][ni], 0, 0, 0);
                    acc[mi][ni] = __builtin_amdgcn_mfma_f32_32x32x16_bf16(
                        al[mi], bh[ni], acc[mi][ni], 0, 0, 0);
                }
        }
    }
    int col = lane & 31;
    int rquad = 4 * (lane >> 5);
    #pragma unroll
    for (int mi = 0; mi < 2; ++mi)
        #pragma unroll
        for (int ni = 0; ni < 2; ++ni) {
            int mbase = mb * 128 + wm * 64 + mi * 32;
            int nbase = nb * 128 + wn * 64 + ni * 32 + col;
            #pragma unroll
            for (int r = 0; r < 16; ++r) {
                int row = (r & 3) + 8 * (r >> 2) + rquad;
                C[(size_t)(mbase + row) * C_H + nbase] = f2h(acc[mi][ni][r]);
            }
        }
}

// ---------------- fused pool-1: sort + attpool-1 + frag emit + layer-2 prep --
__global__ __launch_bounds__(512)
void k_pool1_fused(const float* __restrict__ score, const float* __restrict__ X,
                   const int* __restrict__ src, const int* __restrict__ dst,
                   const float* __restrict__ wbuf,
                   const float* __restrict__ wg, const float* __restrict__ bg,
                   ushort* __restrict__ XFh, ushort* __restrict__ XFl,
                   float* __restrict__ outb,
                   float* __restrict__ selfw1, int* __restrict__ rowst1,
                   int* __restrict__ indeg1, int* __restrict__ csrs,
                   float* __restrict__ csrn) {
    int g = blockIdx.x, t = threadIdx.x;
    __shared__ float sv[C_NPG];
    __shared__ int   si[C_NPG];
    __shared__ int   nooL[C_NPG];
    __shared__ int   olds[C_K1];
    __shared__ float gt[C_K1];
    __shared__ float sd[C_K1];
    __shared__ float red[C_K1];
    __shared__ float an[C_K1];
    __shared__ float Xs[32 * 257];
    __shared__ int   indegL[C_K1];
    __shared__ float degL[C_K1];
    __shared__ float dinvL[C_K1];
    __shared__ int   rowstL[C_K1];
    __shared__ int   cursL[C_K1];

    // ---- bitonic sort of 512 scores (descending) ----
    sv[t] = score[g * C_NPG + t];
    si[t] = t;
    __syncthreads();
    for (int k = 2; k <= C_NPG; k <<= 1)
        for (int j = k >> 1; j > 0; j >>= 1) {
            int ixj = t ^ j;
            if (ixj > t) {
                bool desc = ((t & k) == 0);
                float a = sv[t], b = sv[ixj];
                if (desc ? (a < b) : (a > b)) {
                    sv[t] = b; sv[ixj] = a;
                    int tmp = si[t]; si[t] = si[ixj]; si[ixj] = tmp;
                }
            }
            __syncthreads();
        }
    nooL[si[t]] = (t < C_K1) ? t : -1;
    if (t < C_K1) {
        olds[t]   = si[t];
        gt[t]     = tanhf(sv[t]);
        indegL[t] = 0;
        degL[t]   = 0.f;
    }
    __syncthreads();

    // ---- attpool-1 score pass: one wave per kept row ----
    int w = t >> 6, lane = t & 63;
    float4 wg4 = *(const float4*)&wg[lane * 4];
    float bgv = bg[0];
    for (int r = w; r < C_K1; r += 8) {
        float4 xv = *(const float4*)&X[(size_t)(g * C_NPG + olds[r]) * C_H + lane * 4];
        float s = xv.x * wg4.x + xv.y * wg4.y + xv.z * wg4.z + xv.w * wg4.w;
        #pragma unroll
        for (int m = 32; m; m >>= 1) s += __shfl_xor(s, m, 64);
        if (lane == 0) sd[r] = gt[r] * s + bgv;
    }
    __syncthreads();
    // softmax over 256
    if (t < C_K1) red[t] = sd[t];
    __syncthreads();
    for (int s = 128; s; s >>= 1) { if (t < s) red[t] = fmaxf(red[t], red[t + s]); __syncthreads(); }
    float mx = red[0];
    __syncthreads();
    if (t < C_K1) { float ex = expf(sd[t] - mx); an[t] = ex; red[t] = ex; }
    __syncthreads();
    for (int s = 128; s; s >>= 1) { if (t < s) red[t] += red[t + s]; __syncthreads(); }
    if (t < C_K1) an[t] = an[t] / red[0] * gt[t];
    __syncthreads();
    // weighted sum: 2 halves x 256 cols
    {
        int h = t & 255, half = t >> 8;
        float acc = 0.f;
        for (int n = half * 128; n < half * 128 + 128; ++n)
            acc = fmaf(an[n], X[(size_t)(g * C_NPG + olds[n]) * C_H + h], acc);
        __syncthreads();
        if (half == 1) sd[h] = acc;
        __syncthreads();
        if (half == 0) outb[g * C_H + h] = acc + sd[h];
    }
    __syncthreads();

    // ---- frag emission for GEMM-2: 8 chunks of 32 rows ----
    for (int c = 0; c < 8; ++c) {
        #pragma unroll
        for (int i = 0; i < 4; ++i) {
            int u  = t + 512 * i;           // [0,2048)
            int nl = u >> 6, ln = u & 63;
            int r  = c * 32 + nl;
            float4 v = *(const float4*)&X[(size_t)(g * C_NPG + olds[r]) * C_H + ln * 4];
            float gg = gt[r];
            float* xr = &Xs[nl * 257 + ln * 4];
            xr[0] = v.x * gg; xr[1] = v.y * gg; xr[2] = v.z * gg; xr[3] = v.w * gg;
        }
        __syncthreads();
        #pragma unroll
        for (int i = 0; i < 2; ++i) {
            int cch = t + 512 * i;          // [0,1024)
            int kst = cch >> 6, ln = cch & 63;
            int ml  = ln & 31;
            int kb  = kst * 16 + (ln >> 5) * 8;
            short8 hv, lv;
            #pragma unroll
            for (int j = 0; j < 8; ++j) {
                ushort h, l;
                split_bf16(Xs[ml * 257 + kb + j], h, l);
                hv[j] = (short)h; lv[j] = (short)l;
            }
            size_t base = (size_t)(g * 8 + c) * 8192 + (size_t)cch * 8;
            *(short8*)&XFh[base] = hv;
            *(short8*)&XFl[base] = lv;
        }
        __syncthreads();
    }

    // ---- layer-2 graph prep (all edges of this graph) ----
    for (int i = 0; i < 16; ++i) {
        int e  = g * 8192 + t + 512 * i;
        int ns = nooL[src[e] - g * C_NPG];
        int nd = nooL[dst[e] - g * C_NPG];
        if (ns >= 0 && nd >= 0) {
            atomicAdd(&indegL[nd], 1);
            unsafeAtomicAdd(&degL[nd], wbuf[e]);
        }
    }
    __syncthreads();
    if (t < C_K1) {
        float d = degL[t] + 1.f;
        dinvL[t] = rsqrtf(d);
        selfw1[g * C_K1 + t] = 1.f / d;
        indeg1[g * C_K1 + t] = indegL[t];
        rowstL[t] = indegL[t];
    }
    __syncthreads();
    for (int off = 1; off < C_K1; off <<= 1) {
        int add = 0;
        if (t < C_K1 && t >= off) add = rowstL[t - off];
        __syncthreads();
        if (t < C_K1) rowstL[t] += add;
        __syncthreads();
    }
    if (t < C_K1) {
        int start = g * 8192 + rowstL[t] - indegL[t];
        rowstL[t] = start;
        cursL[t]  = start;
        rowst1[g * C_K1 + t] = start;
    }
    __syncthreads();
    for (int i = 0; i < 16; ++i) {
        int e  = g * 8192 + t + 512 * i;
        int ns = nooL[src[e] - g * C_NPG];
        int nd = nooL[dst[e] - g * C_NPG];
        if (ns >= 0 && nd >= 0) {
            int slot = atomicAdd(&cursL[nd], 1);
            csrs[slot] = g * C_K1 + ns;
            csrn[slot] = dinvL[ns] * wbuf[e] * dinvL[nd];
        }
    }
}

// ---------------- fused pool-2: sort + attpool-2 (accumulate) ----------------
__global__ __launch_bounds__(256)
void k_pool2_fused(const float* __restrict__ score, const float* __restrict__ X,
                   const float* __restrict__ wg, const float* __restrict__ bg,
                   float* __restrict__ outb) {
    int g = blockIdx.x, t = threadIdx.x;
    __shared__ float sv[C_K1];
    __shared__ int   si[C_K1];
    __shared__ int   olds[C_K2];
    __shared__ float gt[C_K2];
    __shared__ float sd[C_K2];
    __shared__ float red[C_K2];
    __shared__ float an[C_K2];
    sv[t] = score[g * C_K1 + t];
    si[t] = t;
    __syncthreads();
    for (int k = 2; k <= C_K1; k <<= 1)
        for (int j = k >> 1; j > 0; j >>= 1) {
            int ixj = t ^ j;
            if (ixj > t) {
                bool desc = ((t & k) == 0);
                float a = sv[t], b = sv[ixj];
                if (desc ? (a < b) : (a > b)) {
                    sv[t] = b; sv[ixj] = a;
                    int tmp = si[t]; si[t] = si[ixj]; si[ixj] = tmp;
                }
            }
            __syncthreads();
        }
    if (t < C_K2) { olds[t] = si[t]; gt[t] = tanhf(sv[t]); }
    __syncthreads();
    int w = t >> 6, lane = t & 63;
    float4 wg4 = *(const float4*)&wg[lane * 4];
    float bgv = bg[0];
    for (int r = w; r < C_K2; r += 4) {
        float4 xv = *(const float4*)&X[(size_t)(g * C_K1 + olds[r]) * C_H + lane * 4];
        float s = xv.x * wg4.x + xv.y * wg4.y + xv.z * wg4.z + xv.w * wg4.w;
        #pragma unroll
        for (int m = 32; m; m >>= 1) s += __shfl_xor(s, m, 64);
        if (lane == 0) sd[r] = gt[r] * s + bgv;
    }
    __syncthreads();
    if (t < C_K2) red[t] = sd[t];
    __syncthreads();
    for (int s = 64; s; s >>= 1) { if (t < s) red[t] = fmaxf(red[t], red[t + s]); __syncthreads(); }
    float mx = red[0];
    __syncthreads();
    if (t < C_K2) { float ex = expf(sd[t] - mx); an[t] = ex; red[t] = ex; }
    __syncthreads();
    for (int s = 64; s; s >>= 1) { if (t < s) red[t] += red[t + s]; __syncthreads(); }
    if (t < C_K2) an[t] = an[t] / red[0] * gt[t];
    __syncthreads();
    float acc = 0.f;
    for (int n = 0; n < C_K2; ++n)
        acc = fmaf(an[n], X[(size_t)(g * C_K1 + olds[n]) * C_H + t], acc);
    outb[g * C_H + t] += acc;
}

// ---------------- projection head ----------------
__global__ void k_head(const float* __restrict__ outb, const float* __restrict__ Wp1,
                       const float* __restrict__ bp1, const float* __restrict__ Wp2,
                       const float* __restrict__ bp2, float* __restrict__ dout) {
    int g = blockIdx.x;
    int t = threadIdx.x;   // 128
    __shared__ float so[C_H];
    so[t] = outb[g * C_H + t];
    so[t + 128] = outb[g * C_H + t + 128];
    __syncthreads();
    float acc = bp1[t];
    for (int k = 0; k < C_H; ++k) acc += so[k] * Wp1[k * C_P + t];
    float hv = fmaxf(acc, 0.f);
    __shared__ float sh[C_P];
    sh[t] = hv; __syncthreads();
    float lg = bp2[t];
    for (int k = 0; k < C_P; ++k) lg += sh[k] * Wp2[k * C_P + t];
    __shared__ float red[C_P];
    red[t] = lg * lg; __syncthreads();
    for (int s = 64; s > 0; s >>= 1) { if (t < s) red[t] += red[t + s]; __syncthreads(); }
    float nrm = fmaxf(sqrtf(red[0]), 1e-12f);
    dout[g * C_P + t] = lg / nrm;
    dout[C_B * C_P + g * C_H + t]       = so[t];
    dout[C_B * C_P + g * C_H + t + 128] = so[t + 128];
}

extern "C" void kernel_launch(void* const* d_in, const int* in_sizes, int n_in,
                              void* d_out, int out_size, void* d_ws, size_t ws_size,
                              hipStream_t stream) {
    const int*   tokens = (const int*)d_in[0];
    const int*   src    = (const int*)d_in[1];
    const int*   dst    = (const int*)d_in[2];
    const float* eattr  = (const float*)d_in[3];
    const float* emb    = (const float*)d_in[4];
    const float* W0     = (const float*)d_in[5];
    const float* b0     = (const float*)d_in[6];
    const float* W1     = (const float*)d_in[7];
    const float* b1     = (const float*)d_in[8];
    const float* p0     = (const float*)d_in[9];
    const float* p1     = (const float*)d_in[10];
    const float* wg     = (const float*)d_in[11];
    const float* bg     = (const float*)d_in[12];
    const float* Wp1    = (const float*)d_in[13];
    const float* bp1    = (const float*)d_in[14];
    const float* Wp2    = (const float*)d_in[15];
    const float* bp2    = (const float*)d_in[16];
    float* out = (float*)d_out;

    float* f = (float*)d_ws;
    size_t o = 0;
    float*  XB    = f + o; o += (size_t)C_N * C_H;     // emb16 early; gcn1 out; layer2: AGG1
    float*  HB    = f + o; o += (size_t)C_N * C_H;     // Hhf fp16 GEMM out (first half)
    ushort* XFh   = (ushort*)(f + o); o += (size_t)C_N * C_H / 2;
    ushort* XFl   = (ushort*)(f + o); o += (size_t)C_N * C_H / 2;
    float*  wbuf  = f + o; o += C_E;
    float*  degb  = f + o; o += C_N;                   // -> selfw (layer 1)
    int*    indegb= (int*)(f + o); o += C_N;           // adjacent to degb: one memset
    float*  dinv  = f + o; o += C_N;
    int*    rowst = (int*)(f + o); o += C_N;
    int*    curs  = (int*)(f + o); o += C_N;
    int*    csrs  = (int*)(f + o); o += C_E;
    float*  csrn  = f + o; o += C_E;
    float*  deg1  = f + o; o += C_B * C_K1;            // selfw1
    int*    indeg1= (int*)(f + o); o += C_B * C_K1;
    int*    rowst1= (int*)(f + o); o += C_B * C_K1;
    float*  outb  = f + o; o += C_B * C_H;
    float*  score = f + o; o += C_N;
    float*  invnp = f + o; o += 16;
    ushort* W0h   = (ushort*)(f + o); o += C_H * C_H / 2;
    ushort* W0l   = (ushort*)(f + o); o += C_H * C_H / 2;
    ushort* W1h   = (ushort*)(f + o); o += C_H * C_H / 2;
    ushort* W1l   = (ushort*)(f + o); o += C_H * C_H / 2;

    ushort* emb16 = (ushort*)XB;                       // dead before gcn_gather1 writes XB
    float*  AGG1  = XB;                                // layer-2 gcn out (16384 rows)
    ushort* Hhf   = (ushort*)HB;                       // fp16 GEMM out (32768 rows)

    hipMemsetAsync(degb, 0, 2 * C_N * sizeof(float), stream);   // degb + indegb

    k_pre<<<8812, 256, 0, stream>>>(emb, emb16, eattr, dst, wbuf, degb, indegb,
                                    W0, W1, W0h, W0l, W1h, W1l, p0, p1, invnp);
    k_st_encode4<<<C_N / 32, 256, 0, stream>>>(tokens, emb16, XFh, XFl);
    k_scan<C_NPG><<<C_B, C_NPG, 0, stream>>>(indegb, rowst, curs, degb, dinv);
    k_csr_scatter<<<C_E / 256, 256, 0, stream>>>(src, dst, wbuf, dinv, curs, csrs, csrn);

    // ---- layer 1 ----
    k_gemm_mfma<<<dim3(C_N / 128, 2), 256, 0, stream>>>(XFh, XFl, W0h, W0l, Hhf);
    k_gcn_gather<<<(C_N * 64) / 256, 256, 0, stream>>>(
        Hhf, rowst, indegb, csrs, csrn, degb, b0, p0, invnp, XB, score, C_N);

    k_pool1_fused<<<C_B, 512, 0, stream>>>(
        score, XB, src, dst, wbuf, wg, bg, XFh, XFl, outb,
        deg1, rowst1, indeg1, csrs, csrn);

    // ---- layer 2 ----
    k_gemm_mfma<<<dim3((C_B * C_K1) / 128, 2), 256, 0, stream>>>(XFh, XFl, W1h, W1l, Hhf);
    k_gcn_gather<<<(C_B * C_K1 * 64) / 256, 256, 0, stream>>>(
        Hhf, rowst1, indeg1, csrs, csrn, deg1, b1, p1, invnp + 1, AGG1, score, C_B * C_K1);

    k_pool2_fused<<<C_B, C_K1, 0, stream>>>(score, AGG1, wg, bg, outb);

    // ---- head ----
    k_head<<<C_B, C_P, 0, stream>>>(outb, Wp1, bp1, Wp2, bp2, out);
}

// Round 8
// 375.296 us; speedup vs baseline: 7.1332x; 1.0809x over previous
//
#include <hip/hip_runtime.h>
#include <hip/hip_bf16.h>

constexpr int C_B   = 64;
constexpr int C_NPG = 512;
constexpr int C_N   = 32768;
constexpr int C_E   = 524288;
constexpr int C_L   = 16;
constexpr int C_H   = 256;
constexpr int C_P   = 128;
constexpr int C_K1  = 256;
constexpr int C_K2  = 128;
constexpr int C_V   = 50000;

typedef __attribute__((ext_vector_type(8)))  short  short8;
typedef __attribute__((ext_vector_type(16))) float  float16;
typedef unsigned short ushort;
typedef unsigned int   uint;

__device__ inline void split_bf16(float x, ushort& h, ushort& l) {
    __hip_bfloat16 bh = __float2bfloat16(x);
    float fh = __bfloat162float(bh);
    __hip_bfloat16 bl = __float2bfloat16(x - fh);
    h = __builtin_bit_cast(ushort, bh);
    l = __builtin_bit_cast(ushort, bl);
}

__device__ inline ushort f2h(float x) {
    return __builtin_bit_cast(ushort, (_Float16)x);
}
__device__ inline float4 h4_to_f4(ushort4 v) {
    return make_float4((float)__builtin_bit_cast(_Float16, v.x),
                       (float)__builtin_bit_cast(_Float16, v.y),
                       (float)__builtin_bit_cast(_Float16, v.z),
                       (float)__builtin_bit_cast(_Float16, v.w));
}

// hybrid bitonic sort, descending: intra-wave rounds via shfl_xor, cross-wave via LDS
template <int NPER>
__device__ inline void bitonic_desc(float& v, int& idx, float* svL, int* siL, int t) {
    #pragma unroll
    for (int k = 2; k <= NPER; k <<= 1) {
        bool desc = ((t & k) == 0);
        #pragma unroll
        for (int j = k >> 1; j > 0; j >>= 1) {
            bool amLo = ((t & j) == 0);
            bool keepMax = (desc == amLo);
            float pv; int pi;
            if (j >= 64) {
                __syncthreads();
                svL[t] = v; siL[t] = idx;
                __syncthreads();
                pv = svL[t ^ j]; pi = siL[t ^ j];
            } else {
                pv = __shfl_xor(v, j, 64);
                pi = __shfl_xor(idx, j, 64);
            }
            bool take = keepMax ? (pv > v) : (pv < v);
            if (take) { v = pv; idx = pi; }
        }
    }
}

// ---------------- fused preprocessing: embcvt | edge_w | wprep | p-norms -----
__global__ void k_pre(const float* __restrict__ emb, ushort* __restrict__ emb16,
                      const float* __restrict__ ea, const int* __restrict__ dst,
                      float* __restrict__ w, float* __restrict__ degb, int* __restrict__ indegb,
                      const float* __restrict__ W0, const float* __restrict__ W1,
                      ushort* __restrict__ W0h, ushort* __restrict__ W0l,
                      ushort* __restrict__ W1h, ushort* __restrict__ W1l,
                      const float* __restrict__ p0, const float* __restrict__ p1,
                      float* __restrict__ invnp) {
    int b = blockIdx.x, t = threadIdx.x;
    __shared__ float r[256];
    if (b < 6250) {                       // emb fp32 -> fp16
        int i = (b * 256 + t) * 8;
        float4 a = *(const float4*)&emb[i];
        float4 c = *(const float4*)&emb[i + 4];
        short8 o;
        o[0] = (short)f2h(a.x); o[1] = (short)f2h(a.y);
        o[2] = (short)f2h(a.z); o[3] = (short)f2h(a.w);
        o[4] = (short)f2h(c.x); o[5] = (short)f2h(c.y);
        o[6] = (short)f2h(c.z); o[7] = (short)f2h(c.w);
        *(short8*)&emb16[i] = o;
    } else if (b < 8298) {                // edge weights + degrees
        int e = (b - 6250) * 256 + t;
        float ww = 0.5f * (ea[2 * e] + ea[2 * e + 1]);
        w[e] = ww;
        int d = dst[e];
        atomicAdd(&degb[d], ww);
        atomicAdd(&indegb[d], 1);
    } else if (b < 8810) {                // W prep -> frag-major hi/lo
        int g = (b - 8298) * 256 + t;
        int which = g >> 16;
        int idx = g & 65535;
        int k = idx >> 8, n = idx & 255;
        float x = (which ? W1 : W0)[idx];
        ushort h, l;
        split_bf16(x, h, l);
        size_t a = ((size_t)(n >> 5) * 16 + (k >> 4)) * 512 + ((k >> 3) & 1) * 256
                 + (n & 31) * 8 + (k & 7);
        if (which) { W1h[a] = h; W1l[a] = l; }
        else       { W0h[a] = h; W0l[a] = l; }
    } else {                              // p-norms
        const float* p = (b == 8810) ? p0 : p1;
        float v = p[t];
        r[t] = v * v; __syncthreads();
        for (int s = 128; s; s >>= 1) { if (t < s) r[t] += r[t + s]; __syncthreads(); }
        if (t == 0) invnp[b - 8810] = rsqrtf(r[0]);
    }
}

// ---------------- per-graph exclusive scan of in-degree + dinv/selfw (L1) ----
template <int NPER>
__global__ void k_scan(const int* __restrict__ indeg, int* __restrict__ rowstart,
                       int* __restrict__ cursor, float* __restrict__ deg,
                       float* __restrict__ dinv) {
    int g = blockIdx.x, t = threadIdx.x;
    int node = g * NPER + t;
    float d = deg[node] + 1.f;
    dinv[node] = rsqrtf(d);
    deg[node]  = 1.f / d;     // selfw in-place
    __shared__ int s[NPER];
    int v = indeg[node];
    s[t] = v;
    __syncthreads();
    for (int off = 1; off < NPER; off <<= 1) {
        int add = (t >= off) ? s[t - off] : 0;
        __syncthreads();
        s[t] += add;
        __syncthreads();
    }
    int start = g * 8192 + s[t] - v;
    rowstart[node] = start;
    cursor[node]   = start;
}

// ---------------- CSR build (layer 1) ----------------
__global__ void k_csr_scatter(const int* __restrict__ src, const int* __restrict__ dst,
                              const float* __restrict__ w, const float* __restrict__ dinv,
                              int* __restrict__ cursor, int* __restrict__ csr_src,
                              float* __restrict__ csr_nrm) {
    int e = blockIdx.x * blockDim.x + threadIdx.x;
    if (e >= C_E) return;
    int s = src[e], d = dst[e];
    int slot = atomicAdd(&cursor[d], 1);
    csr_src[slot] = s;
    csr_nrm[slot] = dinv[s] * w[e] * dinv[d];
}

// ---------------- GCN aggregate (fp16 H rows) + fused pool score -------------
__global__ __launch_bounds__(256)
void k_gcn_gather(const ushort* __restrict__ Hm, const int* __restrict__ rowstart,
                  const int* __restrict__ indeg, const int* __restrict__ csr_src,
                  const float* __restrict__ csr_nrm, const float* __restrict__ selfw,
                  const float* __restrict__ bias, const float* __restrict__ p,
                  const float* __restrict__ invnp, float* __restrict__ Xout,
                  float* __restrict__ score, int nnodes) {
    int n    = (blockIdx.x * blockDim.x + threadIdx.x) >> 6;
    int lane = threadIdx.x & 63;
    if (n >= nnodes) return;
    int h4 = lane * 4;
    float4 hv = h4_to_f4(*(const ushort4*)&Hm[(size_t)n * C_H + h4]);
    float  sw = selfw[n];
    float4 bv = *(const float4*)&bias[h4];
    float4 acc = make_float4(fmaf(hv.x, sw, bv.x), fmaf(hv.y, sw, bv.y),
                             fmaf(hv.z, sw, bv.z), fmaf(hv.w, sw, bv.w));
    int start = rowstart[n], cnt = indeg[n];
    const int*   sp = csr_src + start;
    const float* np = csr_nrm + start;
    #pragma unroll 4
    for (int j = 0; j < cnt; ++j) {
        int   s  = sp[j];
        float nm = np[j];
        float4 xv = h4_to_f4(*(const ushort4*)&Hm[(size_t)s * C_H + h4]);
        acc.x = fmaf(nm, xv.x, acc.x);
        acc.y = fmaf(nm, xv.y, acc.y);
        acc.z = fmaf(nm, xv.z, acc.z);
        acc.w = fmaf(nm, xv.w, acc.w);
    }
    acc.x = fmaxf(acc.x, 0.f); acc.y = fmaxf(acc.y, 0.f);
    acc.z = fmaxf(acc.z, 0.f); acc.w = fmaxf(acc.w, 0.f);
    *(float4*)&Xout[(size_t)n * C_H + h4] = acc;
    float4 pv = *(const float4*)&p[h4];
    float s = acc.x * pv.x + acc.y * pv.y + acc.z * pv.z + acc.w * pv.w;
    #pragma unroll
    for (int m = 32; m; m >>= 1) s += __shfl_xor(s, m, 64);
    if (lane == 0) score[n] = s * invnp[0];
}

// ---------------- ST encoder: fp16 table gather -> frag-major hi/lo ----------
__global__ __launch_bounds__(256)
void k_st_encode4(const int* __restrict__ tokens, const ushort* __restrict__ emb16,
                  ushort* __restrict__ Xh, ushort* __restrict__ Xl) {
    __shared__ float Xs[32 * 257];
    __shared__ int tokS[512];
    int tid = threadIdx.x;
    int blk = blockIdx.x;
    tokS[tid]       = tokens[(size_t)blk * 512 + tid];
    tokS[tid + 256] = tokens[(size_t)blk * 512 + tid + 256];
    __syncthreads();
    int w    = tid >> 6;
    int lane = tid & 63;
    for (int i = 0; i < 8; ++i) {
        int nl = w * 8 + i;
        float4 acc = make_float4(0.f, 0.f, 0.f, 0.f);
        int cnt = 0;
        #pragma unroll
        for (int t = 0; t < C_L; ++t) {
            int tk = tokS[nl * 16 + t];               // wave-uniform
            if (tk != 0) {
                float4 ev = h4_to_f4(*(const ushort4*)&emb16[(size_t)tk * C_H + lane * 4]);
                acc.x += ev.x; acc.y += ev.y; acc.z += ev.z; acc.w += ev.w;
                cnt++;
            }
        }
        float inv = 1.f / fmaxf((float)cnt, 1.f);
        float* xr = &Xs[nl * 257 + lane * 4];
        xr[0] = acc.x * inv; xr[1] = acc.y * inv;
        xr[2] = acc.z * inv; xr[3] = acc.w * inv;
    }
    __syncthreads();
    #pragma unroll
    for (int i = 0; i < 4; ++i) {
        int c    = tid + 256 * i;
        int kst  = c >> 6;
        int ln   = c & 63;
        int ml   = ln & 31;
        int kb   = kst * 16 + (ln >> 5) * 8;
        short8 hv, lv;
        #pragma unroll
        for (int j = 0; j < 8; ++j) {
            ushort h, l;
            split_bf16(Xs[ml * 257 + kb + j], h, l);
            hv[j] = (short)h; lv[j] = (short)l;
        }
        size_t base = (size_t)blk * 8192 + (size_t)c * 8;
        *(short8*)&Xh[base] = hv;
        *(short8*)&Xl[base] = lv;
    }
}

// ---------------- split-bf16 MFMA GEMM -> fp16 output rows -------------------
__global__ __launch_bounds__(256)
void k_gemm_mfma(const ushort* __restrict__ Ah, const ushort* __restrict__ Al,
                 const ushort* __restrict__ Bh, const ushort* __restrict__ Bl,
                 ushort* __restrict__ C) {
    __shared__ short lds[16384];
    int tid  = threadIdx.x;
    int lane = tid & 63;
    int wid  = tid >> 6;
    int wm   = wid & 1, wn = wid >> 1;
    int mb   = blockIdx.x;
    int nb   = blockIdx.y;

    float16 acc[2][2];
    #pragma unroll
    for (int mi = 0; mi < 2; ++mi)
        #pragma unroll
        for (int ni = 0; ni < 2; ++ni)
            #pragma unroll
            for (int r = 0; r < 16; ++r) acc[mi][ni][r] = 0.f;

    for (int kc = 0; kc < 8; ++kc) {
        __syncthreads();
        #pragma unroll
        for (int i = 0; i < 4; ++i) {
            int a  = tid + 256 * i;
            int s  = a >> 9;
            int mt = (a >> 7) & 3;
            int k2 = (a >> 6) & 1;
            int ln = a & 63;
            const ushort* ap = (s ? Al : Ah)
                + (((size_t)(mb * 4 + mt) * 16 + kc * 2 + k2) * 64 + ln) * 8;
            *(int4*)&lds[a * 8] = *(const int4*)ap;
            const ushort* bp = (s ? Bl : Bh)
                + (((size_t)(nb * 4 + mt) * 16 + kc * 2 + k2) * 64 + ln) * 8;
            *(int4*)&lds[8192 + a * 8] = *(const int4*)bp;
        }
        __syncthreads();
        #pragma unroll
        for (int k2 = 0; k2 < 2; ++k2) {
            short8 ah[2], al[2], bh[2], bl[2];
            #pragma unroll
            for (int mi = 0; mi < 2; ++mi) {
                int mt = wm * 2 + mi;
                ah[mi] = *(short8*)&lds[((mt * 2 + k2) * 64 + lane) * 8];
                al[mi] = *(short8*)&lds[(((4 + mt) * 2 + k2) * 64 + lane) * 8];
            }
            #pragma unroll
            for (int ni = 0; ni < 2; ++ni) {
                int nt = wn * 2 + ni;
                bh[ni] = *(short8*)&lds[8192 + ((nt * 2 + k2) * 64 + lane) * 8];
                bl[ni] = *(short8*)&lds[8192 + (((4 + nt) * 2 + k2) * 64 + lane) * 8];
            }
            #pragma unroll
            for (int mi = 0; mi < 2; ++mi)
                #pragma unroll
                for (int ni = 0; ni < 2; ++ni) {
                    acc[mi][ni] = __builtin_amdgcn_mfma_f32_32x32x16_bf16(
                        ah[mi], bh[ni], acc[mi][ni], 0, 0, 0);
                    acc[mi][ni] = __builtin_amdgcn_mfma_f32_32x32x16_bf16(
                        ah[mi], bl[ni], acc[mi][ni], 0, 0, 0);
                    acc[mi][ni] = __builtin_amdgcn_mfma_f32_32x32x16_bf16(
                        al[mi], bh[ni], acc[mi][ni], 0, 0, 0);
                }
        }
    }
    int col = lane & 31;
    int rquad = 4 * (lane >> 5);
    #pragma unroll
    for (int mi = 0; mi < 2; ++mi)
        #pragma unroll
        for (int ni = 0; ni < 2; ++ni) {
            int mbase = mb * 128 + wm * 64 + mi * 32;
            int nbase = nb * 128 + wn * 64 + ni * 32 + col;
            #pragma unroll
            for (int r = 0; r < 16; ++r) {
                int row = (r & 3) + 8 * (r >> 2) + rquad;
                C[(size_t)(mbase + row) * C_H + nbase] = f2h(acc[mi][ni][r]);
            }
        }
}

// ---------------- fused pool-1: sort + attpool-1 + frag emit + layer-2 prep --
__global__ __launch_bounds__(512)
void k_pool1_fused(const float* __restrict__ score, const float* __restrict__ X,
                   const int* __restrict__ src, const int* __restrict__ dst,
                   const float* __restrict__ wbuf,
                   const float* __restrict__ wg, const float* __restrict__ bg,
                   ushort* __restrict__ XFh, ushort* __restrict__ XFl,
                   float* __restrict__ outb,
                   float* __restrict__ selfw1, int* __restrict__ rowst1,
                   int* __restrict__ indeg1, int* __restrict__ csrs,
                   float* __restrict__ csrn) {
    int g = blockIdx.x, t = threadIdx.x;
    int lane = t & 63, w = t >> 6;          // 8 waves
    __shared__ float svL[C_NPG];
    __shared__ int   siL[C_NPG];
    __shared__ int   nooL[C_NPG];
    __shared__ int   olds[C_K1];
    __shared__ float gt[C_K1];
    __shared__ float sd[C_K1];
    __shared__ float red[C_K1];
    __shared__ float an[C_K1];
    __shared__ float wsum[8][C_H];
    __shared__ int   indegL[C_K1];
    __shared__ float degL[C_K1];
    __shared__ float dinvL[C_K1];
    __shared__ int   cursL[C_K1];

    // ---- sort 512 scores descending (hybrid shfl/LDS bitonic) ----
    float v = score[g * C_NPG + t];
    int   idx = t;
    bitonic_desc<C_NPG>(v, idx, svL, siL, t);
    __syncthreads();
    nooL[idx] = (t < C_K1) ? t : -1;
    if (t < C_K1) {
        olds[t]   = idx;
        gt[t]     = tanhf(v);
        indegL[t] = 0;
        degL[t]   = 0.f;
    }
    __syncthreads();

    // ---- attpool-1 scores: 2 threads per kept row ----
    float bgv = bg[0];
    {
        int r = t >> 1, half = t & 1;
        const float* xr = &X[(size_t)(g * C_NPG + olds[r]) * C_H + half * 128];
        const float* wr = &wg[half * 128];
        float s = 0.f;
        #pragma unroll
        for (int kk = 0; kk < 128; kk += 4) {
            float4 xv = *(const float4*)&xr[kk];
            float4 wv = *(const float4*)&wr[kk];
            s += xv.x * wv.x + xv.y * wv.y + xv.z * wv.z + xv.w * wv.w;
        }
        if (half) red[r] = s;
        __syncthreads();
        if (!half) sd[r] = gt[r] * (s + red[r]) + bgv;
        __syncthreads();
    }
    // softmax over 256 via wave 0
    if (w == 0) {
        float m = fmaxf(fmaxf(sd[lane], sd[lane + 64]), fmaxf(sd[lane + 128], sd[lane + 192]));
        #pragma unroll
        for (int mm = 32; mm; mm >>= 1) m = fmaxf(m, __shfl_xor(m, mm, 64));
        if (lane == 0) red[0] = m;
    }
    __syncthreads();
    float mx = red[0];
    if (t < C_K1) an[t] = expf(sd[t] - mx);
    __syncthreads();
    if (w == 0) {
        float s4 = an[lane] + an[lane + 64] + an[lane + 128] + an[lane + 192];
        #pragma unroll
        for (int mm = 32; mm; mm >>= 1) s4 += __shfl_xor(s4, mm, 64);
        if (lane == 0) red[1] = s4;
    }
    __syncthreads();
    if (t < C_K1) an[t] = an[t] / red[1] * gt[t];
    __syncthreads();
    // weighted sum: wave w owns rows w*32..w*32+31, lane owns col-group
    {
        float4 a4 = make_float4(0.f, 0.f, 0.f, 0.f);
        #pragma unroll 4
        for (int r = 0; r < 32; ++r) {
            int rr = w * 32 + r;
            float a = an[rr];
            float4 xv = *(const float4*)&X[(size_t)(g * C_NPG + olds[rr]) * C_H + lane * 4];
            a4.x = fmaf(a, xv.x, a4.x); a4.y = fmaf(a, xv.y, a4.y);
            a4.z = fmaf(a, xv.z, a4.z); a4.w = fmaf(a, xv.w, a4.w);
        }
        *(float4*)&wsum[w][lane * 4] = a4;
        __syncthreads();
        if (t < C_H) {
            float s = wsum[0][t] + wsum[1][t] + wsum[2][t] + wsum[3][t]
                    + wsum[4][t] + wsum[5][t] + wsum[6][t] + wsum[7][t];
            outb[g * C_H + t] = s;
        }
    }

    // ---- frag emission for GEMM-2 directly from global X (no barriers) ----
    #pragma unroll
    for (int i = 0; i < 16; ++i) {
        int u   = t + 512 * i;              // [0,8192)
        int mt  = u >> 10;                  // mtile 0..7
        int c   = u & 1023;
        int kst = c >> 6, ln = c & 63, ml = ln & 31;
        int kb  = kst * 16 + (ln >> 5) * 8;
        int r   = mt * 32 + ml;
        const float* xp = &X[(size_t)(g * C_NPG + olds[r]) * C_H + kb];
        float gg = gt[r];
        float4 a = *(const float4*)&xp[0];
        float4 b = *(const float4*)&xp[4];
        float e8[8] = {a.x * gg, a.y * gg, a.z * gg, a.w * gg,
                       b.x * gg, b.y * gg, b.z * gg, b.w * gg};
        short8 hv, lv;
        #pragma unroll
        for (int j = 0; j < 8; ++j) {
            ushort h, l;
            split_bf16(e8[j], h, l);
            hv[j] = (short)h; lv[j] = (short)l;
        }
        size_t base = (size_t)(g * 8 + mt) * 8192 + (size_t)c * 8;
        *(short8*)&XFh[base] = hv;
        *(short8*)&XFl[base] = lv;
    }

    // ---- layer-2 graph prep: degree pass with register-cached edges ----
    int   nsR[16], ndR[16];
    float wwR[16];
    #pragma unroll
    for (int i = 0; i < 16; ++i) {
        int e  = g * 8192 + t + 512 * i;
        int ns = nooL[src[e] - g * C_NPG];
        int nd = nooL[dst[e] - g * C_NPG];
        float ww = wbuf[e];
        nsR[i] = ns; ndR[i] = nd; wwR[i] = ww;
        if (ns >= 0 && nd >= 0) {
            atomicAdd(&indegL[nd], 1);
            unsafeAtomicAdd(&degL[nd], ww);
        }
    }
    __syncthreads();
    if (t < C_K1) {
        float d = degL[t] + 1.f;
        dinvL[t] = rsqrtf(d);
        selfw1[g * C_K1 + t] = 1.f / d;
        indeg1[g * C_K1 + t] = indegL[t];
    }
    if (w == 0) {                           // exclusive scan of 256 indeg via one wave
        int a0 = indegL[lane * 4], a1 = indegL[lane * 4 + 1];
        int a2 = indegL[lane * 4 + 2], a3 = indegL[lane * 4 + 3];
        int s4 = a0 + a1 + a2 + a3;
        int sc = s4;
        #pragma unroll
        for (int off = 1; off < 64; off <<= 1) {
            int pv = __shfl_up(sc, off, 64);
            if (lane >= off) sc += pv;
        }
        int base = g * 8192 + (sc - s4);
        cursL[lane * 4]     = base;
        cursL[lane * 4 + 1] = base + a0;
        cursL[lane * 4 + 2] = base + a0 + a1;
        cursL[lane * 4 + 3] = base + a0 + a1 + a2;
        rowst1[g * C_K1 + lane * 4]     = base;
        rowst1[g * C_K1 + lane * 4 + 1] = base + a0;
        rowst1[g * C_K1 + lane * 4 + 2] = base + a0 + a1;
        rowst1[g * C_K1 + lane * 4 + 3] = base + a0 + a1 + a2;
    }
    __syncthreads();
    #pragma unroll
    for (int i = 0; i < 16; ++i) {
        int ns = nsR[i], nd = ndR[i];
        if (ns >= 0 && nd >= 0) {
            int slot = atomicAdd(&cursL[nd], 1);
            csrs[slot] = g * C_K1 + ns;
            csrn[slot] = dinvL[ns] * wwR[i] * dinvL[nd];
        }
    }
}

// ---------------- fused pool-2: sort + attpool-2 (accumulate) ----------------
__global__ __launch_bounds__(256)
void k_pool2_fused(const float* __restrict__ score, const float* __restrict__ X,
                   const float* __restrict__ wg, const float* __restrict__ bg,
                   float* __restrict__ outb) {
    int g = blockIdx.x, t = threadIdx.x;
    int lane = t & 63, w = t >> 6;          // 4 waves
    __shared__ float svL[C_K1];
    __shared__ int   siL[C_K1];
    __shared__ int   olds[C_K2];
    __shared__ float gt[C_K2];
    __shared__ float sd[C_K2];
    __shared__ float red[C_K2];
    __shared__ float an[C_K2];
    __shared__ float wsum[4][C_H];

    float v = score[g * C_K1 + t];
    int   idx = t;
    bitonic_desc<C_K1>(v, idx, svL, siL, t);
    __syncthreads();
    if (t < C_K2) { olds[t] = idx; gt[t] = tanhf(v); }
    __syncthreads();

    float bgv = bg[0];
    {
        int r = t >> 1, half = t & 1;       // 128 rows x 2
        const float* xr = &X[(size_t)(g * C_K1 + olds[r]) * C_H + half * 128];
        const float* wr = &wg[half * 128];
        float s = 0.f;
        #pragma unroll
        for (int kk = 0; kk < 128; kk += 4) {
            float4 xv = *(const float4*)&xr[kk];
            float4 wv = *(const float4*)&wr[kk];
            s += xv.x * wv.x + xv.y * wv.y + xv.z * wv.z + xv.w * wv.w;
        }
        if (half) red[r] = s;
        __syncthreads();
        if (!half) sd[r] = gt[r] * (s + red[r]) + bgv;
        __syncthreads();
    }
    if (w == 0) {
        float m = fmaxf(sd[lane], sd[lane + 64]);
        #pragma unroll
        for (int mm = 32; mm; mm >>= 1) m = fmaxf(m, __shfl_xor(m, mm, 64));
        if (lane == 0) red[0] = m;
    }
    __syncthreads();
    float mx = red[0];
    if (t < C_K2) an[t] = expf(sd[t] - mx);
    __syncthreads();
    if (w == 0) {
        float s2 = an[lane] + an[lane + 64];
        #pragma unroll
        for (int mm = 32; mm; mm >>= 1) s2 += __shfl_xor(s2, mm, 64);
        if (lane == 0) red[1] = s2;
    }
    __syncthreads();
    if (t < C_K2) an[t] = an[t] / red[1] * gt[t];
    __syncthreads();
    {
        float4 a4 = make_float4(0.f, 0.f, 0.f, 0.f);
        #pragma unroll 4
        for (int r = 0; r < 32; ++r) {
            int rr = w * 32 + r;
            float a = an[rr];
            float4 xv = *(const float4*)&X[(size_t)(g * C_K1 + olds[rr]) * C_H + lane * 4];
            a4.x = fmaf(a, xv.x, a4.x); a4.y = fmaf(a, xv.y, a4.y);
            a4.z = fmaf(a, xv.z, a4.z); a4.w = fmaf(a, xv.w, a4.w);
        }
        *(float4*)&wsum[w][lane * 4] = a4;
        __syncthreads();
        float s = wsum[0][t] + wsum[1][t] + wsum[2][t] + wsum[3][t];
        outb[g * C_H + t] += s;
    }
}

// ---------------- projection head ----------------
__global__ void k_head(const float* __restrict__ outb, const float* __restrict__ Wp1,
                       const float* __restrict__ bp1, const float* __restrict__ Wp2,
                       const float* __restrict__ bp2, float* __restrict__ dout) {
    int g = blockIdx.x;
    int t = threadIdx.x;   // 128
    __shared__ float so[C_H];
    so[t] = outb[g * C_H + t];
    so[t + 128] = outb[g * C_H + t + 128];
    __syncthreads();
    float acc = bp1[t];
    for (int k = 0; k < C_H; ++k) acc += so[k] * Wp1[k * C_P + t];
    float hv = fmaxf(acc, 0.f);
    __shared__ float sh[C_P];
    sh[t] = hv; __syncthreads();
    float lg = bp2[t];
    for (int k = 0; k < C_P; ++k) lg += sh[k] * Wp2[k * C_P + t];
    __shared__ float red[C_P];
    red[t] = lg * lg; __syncthreads();
    for (int s = 64; s > 0; s >>= 1) { if (t < s) red[t] += red[t + s]; __syncthreads(); }
    float nrm = fmaxf(sqrtf(red[0]), 1e-12f);
    dout[g * C_P + t] = lg / nrm;
    dout[C_B * C_P + g * C_H + t]       = so[t];
    dout[C_B * C_P + g * C_H + t + 128] = so[t + 128];
}

extern "C" void kernel_launch(void* const* d_in, const int* in_sizes, int n_in,
                              void* d_out, int out_size, void* d_ws, size_t ws_size,
                              hipStream_t stream) {
    const int*   tokens = (const int*)d_in[0];
    const int*   src    = (const int*)d_in[1];
    const int*   dst    = (const int*)d_in[2];
    const float* eattr  = (const float*)d_in[3];
    const float* emb    = (const float*)d_in[4];
    const float* W0     = (const float*)d_in[5];
    const float* b0     = (const float*)d_in[6];
    const float* W1     = (const float*)d_in[7];
    const float* b1     = (const float*)d_in[8];
    const float* p0     = (const float*)d_in[9];
    const float* p1     = (const float*)d_in[10];
    const float* wg     = (const float*)d_in[11];
    const float* bg     = (const float*)d_in[12];
    const float* Wp1    = (const float*)d_in[13];
    const float* bp1    = (const float*)d_in[14];
    const float* Wp2    = (const float*)d_in[15];
    const float* bp2    = (const float*)d_in[16];
    float* out = (float*)d_out;

    float* f = (float*)d_ws;
    size_t o = 0;
    float*  XB    = f + o; o += (size_t)C_N * C_H;
    float*  HB    = f + o; o += (size_t)C_N * C_H;
    ushort* XFh   = (ushort*)(f + o); o += (size_t)C_N * C_H / 2;
    ushort* XFl   = (ushort*)(f + o); o += (size_t)C_N * C_H / 2;
    float*  wbuf  = f + o; o += C_E;
    float*  degb  = f + o; o += C_N;
    int*    indegb= (int*)(f + o); o += C_N;
    float*  dinv  = f + o; o += C_N;
    int*    rowst = (int*)(f + o); o += C_N;
    int*    curs  = (int*)(f + o); o += C_N;
    int*    csrs  = (int*)(f + o); o += C_E;
    float*  csrn  = f + o; o += C_E;
    float*  deg1  = f + o; o += C_B * C_K1;
    int*    indeg1= (int*)(f + o); o += C_B * C_K1;
    int*    rowst1= (int*)(f + o); o += C_B * C_K1;
    float*  outb  = f + o; o += C_B * C_H;
    float*  score = f + o; o += C_N;
    float*  invnp = f + o; o += 16;
    ushort* W0h   = (ushort*)(f + o); o += C_H * C_H / 2;
    ushort* W0l   = (ushort*)(f + o); o += C_H * C_H / 2;
    ushort* W1h   = (ushort*)(f + o); o += C_H * C_H / 2;
    ushort* W1l   = (ushort*)(f + o); o += C_H * C_H / 2;

    ushort* emb16 = (ushort*)XB;
    float*  AGG1  = XB;
    ushort* Hhf   = (ushort*)HB;

    hipMemsetAsync(degb, 0, 2 * C_N * sizeof(float), stream);

    k_pre<<<8812, 256, 0, stream>>>(emb, emb16, eattr, dst, wbuf, degb, indegb,
                                    W0, W1, W0h, W0l, W1h, W1l, p0, p1, invnp);
    k_st_encode4<<<C_N / 32, 256, 0, stream>>>(tokens, emb16, XFh, XFl);
    k_scan<C_NPG><<<C_B, C_NPG, 0, stream>>>(indegb, rowst, curs, degb, dinv);
    k_csr_scatter<<<C_E / 256, 256, 0, stream>>>(src, dst, wbuf, dinv, curs, csrs, csrn);

    // ---- layer 1 ----
    k_gemm_mfma<<<dim3(C_N / 128, 2), 256, 0, stream>>>(XFh, XFl, W0h, W0l, Hhf);
    k_gcn_gather<<<(C_N * 64) / 256, 256, 0, stream>>>(
        Hhf, rowst, indegb, csrs, csrn, degb, b0, p0, invnp, XB, score, C_N);

    k_pool1_fused<<<C_B, 512, 0, stream>>>(
        score, XB, src, dst, wbuf, wg, bg, XFh, XFl, outb,
        deg1, rowst1, indeg1, csrs, csrn);

    // ---- layer 2 ----
    k_gemm_mfma<<<dim3((C_B * C_K1) / 128, 2), 256, 0, stream>>>(XFh, XFl, W1h, W1l, Hhf);
    k_gcn_gather<<<(C_B * C_K1 * 64) / 256, 256, 0, stream>>>(
        Hhf, rowst1, indeg1, csrs, csrn, deg1, b1, p1, invnp + 1, AGG1, score, C_B * C_K1);

    k_pool2_fused<<<C_B, C_K1, 0, stream>>>(score, AGG1, wg, bg, outb);

    // ---- head ----
    k_head<<<C_B, C_P, 0, stream>>>(outb, Wp1, bp1, Wp2, bp2, out);
}